// Round 5
// baseline (1072.954 us; speedup 1.0000x reference)
//
#include <hip/hip_runtime.h>
#include <math.h>

#define HW   16384           // 128*128
#define PS   16900           // 130*130 f32 padded plane
#define PSH  17160           // 130*132 bf16 padded plane (stride 132)
#define SH   132

typedef __attribute__((ext_vector_type(8))) short bf16x8;
typedef __attribute__((ext_vector_type(4))) float f32x4;

__device__ inline unsigned short f2bf(float x) {
    unsigned int u = __float_as_uint(x);
    unsigned int r = (u + 0x7fffu + ((u >> 16) & 1u)) >> 16;
    return (unsigned short)r;
}
__device__ inline float bf2f(unsigned short h) {
    return __uint_as_float(((unsigned int)h) << 16);
}

// ---- zero the pad ring of nch f32 padded planes (stride 130) ---------------
__global__ __launch_bounds__(256) void zero_ring_k(float* __restrict__ base, int nch) {
    int t = blockIdx.x * 256 + threadIdx.x;
    if (t >= nch * 516) return;
    int ch = t / 516, rp = t - ch * 516;
    int row, col;
    if (rp < 130)      { row = 0;   col = rp; }
    else if (rp < 260) { row = 129; col = rp - 130; }
    else { int rem = rp - 260; row = 1 + (rem >> 1); col = (rem & 1) ? 129 : 0; }
    base[(size_t)ch * PS + row * 130 + col] = 0.0f;
}

// ---- zero the pad ring of nch bf16 padded planes (stride 132) --------------
__global__ __launch_bounds__(256) void zero_ring_h_k(unsigned short* __restrict__ base, int nch) {
    int t = blockIdx.x * 256 + threadIdx.x;
    if (t >= nch * 520) return;
    int ch = t / 520, rp = t - ch * 520;
    int row, col;
    if (rp < 132)      { row = 0;   col = rp; }
    else if (rp < 264) { row = 129; col = rp - 132; }
    else { int rem = rp - 264; row = 1 + (rem >> 1); col = (rem & 1) ? 129 : 0; }
    base[(size_t)ch * PSH + row * SH + col] = 0;
}

// ---- bilinear upsample (align_corners) 32x32 -> 128x128, into padded cc ----
__global__ __launch_bounds__(256) void upsample_k(const float* __restrict__ x,
                                                  float* __restrict__ ccpad) {
    int c = blockIdx.y;
    int idx = blockIdx.x * 256 + threadIdx.x;
    if (idx >= PS) return;
    int r = idx / 130, s = idx - r * 130;
    float val = 0.0f;
    if (r >= 1 && r <= 128 && s >= 1 && s <= 128) {
        int i = r - 1, j = s - 1;
        float yf = (float)i * (31.0f / 127.0f);
        float xf = (float)j * (31.0f / 127.0f);
        int y0 = min((int)yf, 31); int y1 = min(y0 + 1, 31);
        int x0 = min((int)xf, 31); int x1 = min(x0 + 1, 31);
        float wy = yf - (float)y0, wx = xf - (float)x0;
        const float* xc = x + (size_t)c * 1024;
        float a = xc[y0 * 32 + x0] * (1.0f - wx) + xc[y0 * 32 + x1] * wx;
        float b = xc[y1 * 32 + x0] * (1.0f - wx) + xc[y1 * 32 + x1] * wx;
        val = a * (1.0f - wy) + b * wy;
    }
    ccpad[(size_t)c * PS + idx] = val;
}

// ---- 1x1 conv GEMM + sigmoid ----------------------------------------------
__global__ __launch_bounds__(256) void gemm1x1_sig_k(const float* __restrict__ wmat,
                                                     const float* __restrict__ in,
                                                     float* __restrict__ out) {
    __shared__ float wl[2048];
    int tid = threadIdx.x;
    int o0 = blockIdx.y << 3;
    for (int i = tid; i < 2048; i += 256) wl[i] = wmat[(o0 << 8) + i];
    __syncthreads();
    int p = (blockIdx.x << 10) + (tid << 2);
    float4 acc[8];
#pragma unroll
    for (int j = 0; j < 8; ++j) acc[j] = make_float4(0.f, 0.f, 0.f, 0.f);
    for (int c = 0; c < 256; ++c) {
        float4 z = *(const float4*)(in + (size_t)c * HW + p);
#pragma unroll
        for (int j = 0; j < 8; ++j) {
            float wj = wl[(j << 8) + c];
            acc[j].x += wj * z.x; acc[j].y += wj * z.y;
            acc[j].z += wj * z.z; acc[j].w += wj * z.w;
        }
    }
#pragma unroll
    for (int j = 0; j < 8; ++j) {
        float4 r;
        r.x = 1.0f / (1.0f + expf(-acc[j].x));
        r.y = 1.0f / (1.0f + expf(-acc[j].y));
        r.z = 1.0f / (1.0f + expf(-acc[j].z));
        r.w = 1.0f / (1.0f + expf(-acc[j].w));
        *(float4*)(out + (size_t)(o0 + j) * HW + p) = r;
    }
}

// ---- 1x1 conv GEMM, writes into f32 padded planes (Cf -> ccpad hi) ---------
__global__ __launch_bounds__(256) void gemm1x1_pad_k(const float* __restrict__ wmat,
                                                     const float* __restrict__ in,
                                                     float* __restrict__ outpad) {
    __shared__ float wl[2048];
    int tid = threadIdx.x;
    int o0 = blockIdx.y << 3;
    for (int i = tid; i < 2048; i += 256) wl[i] = wmat[(o0 << 8) + i];
    __syncthreads();
    int p = (blockIdx.x << 10) + (tid << 2);
    float4 acc[8];
#pragma unroll
    for (int j = 0; j < 8; ++j) acc[j] = make_float4(0.f, 0.f, 0.f, 0.f);
    for (int c = 0; c < 256; ++c) {
        float4 z = *(const float4*)(in + (size_t)c * HW + p);
#pragma unroll
        for (int j = 0; j < 8; ++j) {
            float wj = wl[(j << 8) + c];
            acc[j].x += wj * z.x; acc[j].y += wj * z.y;
            acc[j].z += wj * z.z; acc[j].w += wj * z.w;
        }
    }
    int h = p >> 7, w = p & 127;
#pragma unroll
    for (int j = 0; j < 8; ++j) {
        float* dst = outpad + (size_t)(o0 + j) * PS + (h + 1) * 130 + (w + 1);
        dst[0] = acc[j].x; dst[1] = acc[j].y; dst[2] = acc[j].z; dst[3] = acc[j].w;
    }
}

// ---- u[c,h,w] = sum_k L[c,h,k]*v[c,k,w] + L[c,h,w] -------------------------
__global__ __launch_bounds__(256) void u_matmul_k(const float* __restrict__ llf,
                                                  const float* __restrict__ v,
                                                  float* __restrict__ u) {
    int c = blockIdx.y;
    const float* L = llf + (size_t)c * HW;
    const float* V = v   + (size_t)c * HW;
    float*       U = u   + (size_t)c * HW;
    int tid = threadIdx.x;
    int ty = tid >> 4, tx = tid & 15;
    int r0 = (blockIdx.x << 6) + (ty << 2);
    int w0 = tx << 3;
    float acc[4][8] = {};
    for (int k = 0; k < 128; ++k) {
        float a[4];
#pragma unroll
        for (int i = 0; i < 4; ++i) a[i] = L[(r0 + i) * 128 + k];
        float4 b0 = *(const float4*)(V + k * 128 + w0);
        float4 b1 = *(const float4*)(V + k * 128 + w0 + 4);
        float bv[8] = {b0.x, b0.y, b0.z, b0.w, b1.x, b1.y, b1.z, b1.w};
#pragma unroll
        for (int i = 0; i < 4; ++i)
#pragma unroll
            for (int j = 0; j < 8; ++j) acc[i][j] += a[i] * bv[j];
    }
#pragma unroll
    for (int i = 0; i < 4; ++i) {
#pragma unroll
        for (int j = 0; j < 8; ++j) acc[i][j] += L[(r0 + i) * 128 + w0 + j];
        *(float4*)(U + (r0 + i) * 128 + w0)     = make_float4(acc[i][0], acc[i][1], acc[i][2], acc[i][3]);
        *(float4*)(U + (r0 + i) * 128 + w0 + 4) = make_float4(acc[i][4], acc[i][5], acc[i][6], acc[i][7]);
    }
}

// ---- convert 512 f32 padded planes (stride 130) -> bf16 planes (stride 132)
__global__ __launch_bounds__(256) void cvt_bf16_k(const float* __restrict__ src,
                                                  unsigned short* __restrict__ dst) {
    int t = blockIdx.x * 256 + threadIdx.x;   // 512*16900 = 8,652,800 exactly
    int c = t / PS, r = t - c * PS;
    int row = r / 130, col = r - row * 130;
    dst[(size_t)c * PSH + row * SH + col] = f2bf(src[t]);
}

// ---- weights (O,C,3,3) f32 -> [k][o][c] bf16 (O=256) -----------------------
__global__ __launch_bounds__(256) void tr_ocK_k(const float* __restrict__ w,
                                                unsigned short* __restrict__ dst, int C) {
    int t = blockIdx.x * 256 + threadIdx.x;
    if (t >= 9 * 256 * C) return;
    int c = t % C; int rest = t / C; int o = rest & 255; int k = rest >> 8;
    dst[t] = f2bf(w[(size_t)o * C * 9 + c * 9 + k]);
}

// ---- p_w (18,512,3,3) f32 -> [k][32][512] bf16, zero-padded to 32 o --------
__global__ __launch_bounds__(256) void tr_pw_k(const float* __restrict__ w,
                                               unsigned short* __restrict__ dst) {
    int t = blockIdx.x * 256 + threadIdx.x;
    if (t >= 9 * 32 * 512) return;
    int c = t & 511; int rest = t >> 9; int o = rest & 31; int k = rest >> 5;
    dst[t] = (o < 18) ? f2bf(w[(size_t)o * 4608 + c * 9 + k]) : (unsigned short)0;
}

// ============ offset conv 512->18: channel-split partials ===================
// grid 512: each block = 32o x 128px x 128ch partial -> pbuf[cg][32][HW] f32
__global__ __launch_bounds__(256, 2) void off_part_k(
        const unsigned short* __restrict__ cch,   // 512 bf16 planes PSH
        const unsigned short* __restrict__ pwTh,  // [9][32][512] bf16
        float* __restrict__ pbuf) {               // [4][32][HW] f32
    __shared__ __align__(16) unsigned short Bs[128][40];
    int b = blockIdx.x;
    int xcd = b & 7, slot = b >> 3;               // 64 slots
    int hrow = (xcd << 4) + (slot >> 2);
    int cg = slot & 3, c0 = cg << 7;
    int tid = threadIdx.x;
    int wv = tid >> 6, lane = tid & 63;
    int wr = wv >> 1, wc = wv & 1;                // o-half(16) x px-half(64)
    int lr = lane & 15, lg = lane >> 4;
    int px = tid & 127, sg = tid >> 7;
    f32x4 acc[4];
#pragma unroll
    for (int j = 0; j < 4; ++j) acc[j] = (f32x4){0.f, 0.f, 0.f, 0.f};

    for (int kt = 0; kt < 9; ++kt) {
        int dy = kt / 3 - 1, dx = kt % 3 - 1;
        const unsigned short* src = cch + (size_t)(hrow + dy + 1) * SH + (px + dx + 1);
        for (int ksl = 0; ksl < 128; ksl += 32) {
            __syncthreads();
#pragma unroll
            for (int q = 0; q < 4; ++q) {
                unsigned short pk[4];
#pragma unroll
                for (int e = 0; e < 4; ++e) {
                    int c = c0 + ksl + (sg << 4) + (q << 2) + e;
                    pk[e] = src[(size_t)c * PSH];
                }
                *(short4*)&Bs[px][(sg << 4) + (q << 2)] = *(short4*)pk;
            }
            __syncthreads();
            bf16x8 af, bfr[4];
            af = *(const bf16x8*)(pwTh + (size_t)kt * 16384
                                  + (size_t)((wr << 4) + lr) * 512 + c0 + ksl + (lg << 3));
#pragma unroll
            for (int ni = 0; ni < 4; ++ni) {
                int n = (wc << 6) + (ni << 4) + lr;
                bfr[ni] = *(const bf16x8*)(&Bs[n][lg << 3]);
            }
#pragma unroll
            for (int ni = 0; ni < 4; ++ni)
                acc[ni] = __builtin_amdgcn_mfma_f32_16x16x32_bf16(af, bfr[ni], acc[ni], 0, 0, 0);
        }
    }
#pragma unroll
    for (int ni = 0; ni < 4; ++ni)
#pragma unroll
        for (int r = 0; r < 4; ++r) {
            int o = (wr << 4) + (lg << 2) + r;
            int p = (hrow << 7) + (wc << 6) + (ni << 4) + lr;
            pbuf[(size_t)((cg << 5) + o) * HW + p] = acc[ni][r];
        }
}

// ---- per-(pixel,k): sum 4 partials, 4 gather indices + bilinear weights ----
__global__ __launch_bounds__(256) void make_idx_k(const float* __restrict__ pbuf,
                                                  const float* __restrict__ pb,
                                                  int4* __restrict__ IDX,
                                                  float4* __restrict__ WT) {
    int t = blockIdx.x * 256 + threadIdx.x;
    if (t >= 9 * HW) return;
    int k = t >> 14, p = t & 16383;
    int h = p >> 7, w = p & 127;
    float ox = 0.f, oy = 0.f;
#pragma unroll
    for (int cg = 0; cg < 4; ++cg) {
        ox += pbuf[(size_t)((cg << 5) + k) * HW + p];
        oy += pbuf[(size_t)((cg << 5) + 9 + k) * HW + p];
    }
    float px = ox + pb[k]     + (float)(k / 3 - 1) + (float)(h + 1);
    float py = oy + pb[9 + k] + (float)(k % 3 - 1) + (float)(w + 1);
    float fx = floorf(px), fy = floorf(py);
    float x0 = fminf(fmaxf(fx,        0.f), 129.f);
    float x1 = fminf(fmaxf(fx + 1.0f, 0.f), 129.f);
    float y0 = fminf(fmaxf(fy,        0.f), 129.f);
    float y1 = fminf(fmaxf(fy + 1.0f, 0.f), 129.f);
    float pxc = fminf(fmaxf(px, 0.f), 129.f);
    float pyc = fminf(fmaxf(py, 0.f), 129.f);
    float gx0 = 1.0f + x0 - pxc, gx1 = 1.0f - x1 + pxc;
    float gy0 = 1.0f + y0 - pyc, gy1 = 1.0f - y1 + pyc;
    int ix0 = (int)x0, ix1 = (int)x1, iy0 = (int)y0, iy1 = (int)y1;
    IDX[t] = make_int4(ix0 * SH + iy0, ix1 * SH + iy1, ix0 * SH + iy1, ix1 * SH + iy0);
    WT[t]  = make_float4(gx0 * gy0, gx1 * gy1, gx0 * gy1, gx1 * gy0);
}

// ============ deformable contraction: kt-split 3-way, 256o x 32px tiles =====
// grid 1536 (6 blocks/CU): kg g handles kt 3g..3g+2, writes f32 partial Pg.
__global__ __launch_bounds__(256, 6) void fam3_k(
        const unsigned short* __restrict__ cch,    // 512 bf16 planes PSH
        const unsigned short* __restrict__ dcwTh,  // [9][256][512] bf16
        const int4* __restrict__ IDX, const float4* __restrict__ WT,
        float* __restrict__ P0, float* __restrict__ P1, float* __restrict__ P2) {
    __shared__ __align__(16) unsigned short Bs[32][40];
    int b = blockIdx.x;
    int xcd = b & 7, s = b >> 3;           // 192 slots per XCD pass
    int kg = s >> 6, sl = s & 63;
    int nt = (xcd << 6) + sl;              // XCD owns 64 contiguous n-tiles
    int hrow = nt >> 2, pc0 = (nt & 3) << 5;
    int tid = threadIdx.x;
    int wv = tid >> 6, lane = tid & 63;
    int lr = lane & 15, lg = lane >> 4;
    int pxl = tid & 31, cg = tid >> 5;     // 8 c-groups of 4 channels
    int p = (hrow << 7) + pc0 + pxl;
    float* P = (kg == 0) ? P0 : (kg == 1 ? P1 : P2);
    f32x4 acc[4][2];
#pragma unroll
    for (int i = 0; i < 4; ++i)
#pragma unroll
        for (int j = 0; j < 2; ++j) acc[i][j] = (f32x4){0.f, 0.f, 0.f, 0.f};

    for (int kt = kg * 3; kt < kg * 3 + 3; ++kt) {
        int4   id = IDX[(kt << 14) + p];
        float4 wt = WT [(kt << 14) + p];
        const unsigned short* dwk = dcwTh + (size_t)kt * 131072;
        for (int ks = 0; ks < 512; ks += 32) {
            __syncthreads();
            unsigned short pk[4];
#pragma unroll
            for (int e = 0; e < 4; ++e) {
                int c = ks + (cg << 2) + e;
                const unsigned short* cb = cch + (size_t)c * PSH;
                float val = wt.x * bf2f(cb[id.x]) + wt.y * bf2f(cb[id.y])
                          + wt.z * bf2f(cb[id.z]) + wt.w * bf2f(cb[id.w]);
                pk[e] = f2bf(val);
            }
            *(short4*)&Bs[pxl][cg << 2] = *(short4*)pk;
            __syncthreads();
            bf16x8 af[4], bfr[2];
#pragma unroll
            for (int mi = 0; mi < 4; ++mi) {
                int o = (wv << 6) + (mi << 4) + lr;
                af[mi] = *(const bf16x8*)(dwk + (size_t)o * 512 + ks + (lg << 3));
            }
#pragma unroll
            for (int ni = 0; ni < 2; ++ni) {
                int n = (ni << 4) + lr;
                bfr[ni] = *(const bf16x8*)(&Bs[n][lg << 3]);
            }
#pragma unroll
            for (int mi = 0; mi < 4; ++mi)
#pragma unroll
                for (int ni = 0; ni < 2; ++ni)
                    acc[mi][ni] = __builtin_amdgcn_mfma_f32_16x16x32_bf16(
                        af[mi], bfr[ni], acc[mi][ni], 0, 0, 0);
        }
    }
#pragma unroll
    for (int mi = 0; mi < 4; ++mi)
#pragma unroll
        for (int ni = 0; ni < 2; ++ni)
#pragma unroll
            for (int r = 0; r < 4; ++r) {
                int o   = (wv << 6) + (mi << 4) + (lg << 2) + r;
                int pxx = pc0 + (ni << 4) + lr;
                P[(size_t)o * HW + (hrow << 7) + pxx] = acc[mi][ni][r];
            }
}

// ---- famh = bf16(P0+P1+P2+Cf), into padded planes --------------------------
__global__ __launch_bounds__(256) void fam_reduce_k(
        const float* __restrict__ P0, const float* __restrict__ P1,
        const float* __restrict__ P2, const unsigned short* __restrict__ cch,
        unsigned short* __restrict__ famh) {
    int t = blockIdx.x * 256 + threadIdx.x;    // 256*HW exactly
    int o = t >> 14, pp = t & 16383;
    int h = pp >> 7, w = pp & 127;
    float cf = bf2f(cch[(size_t)(256 + o) * PSH + (h + 1) * SH + (w + 1)]);
    float v = P0[t] + P1[t] + P2[t] + cf;
    famh[(size_t)o * PSH + (h + 1) * SH + (w + 1)] = f2bf(v);
}

// ============ 3x3 conv 256->256: o-split, 128o x 32px tiles + BN + ReLU =====
// grid 1024 (4 blocks/CU).
__global__ __launch_bounds__(256, 4) void conv3_k(
        const unsigned short* __restrict__ inh,   // 256 bf16 planes PSH, ring=0
        const unsigned short* __restrict__ wTh,   // [9][256][256] bf16
        const float* __restrict__ gam, const float* __restrict__ bet,
        const float* __restrict__ mean, const float* __restrict__ var,
        float* __restrict__ out_flat,             // [256][HW] f32
        unsigned short* __restrict__ out_padh) {  // optional bf16 planes
    __shared__ __align__(16) unsigned short Bs[32][40];
    __shared__ float scs[128], bis[128];
    int b = blockIdx.x;
    int xcd = b & 7, s = b >> 3;           // 128 slots
    int oh = s >> 6, sl = s & 63;
    int nt = (xcd << 6) + sl;
    int hrow = nt >> 2, pc0 = (nt & 3) << 5;
    int o0 = oh << 7;
    int tid = threadIdx.x;
    int wv = tid >> 6, lane = tid & 63;
    int wr = wv >> 1, wc = wv & 1;         // o-64-half x px-16-half
    int lr = lane & 15, lg = lane >> 4;
    int pxl = tid & 31, cg = tid >> 5;
    if (tid < 128) {
        int o = o0 + tid;
        float sc = gam[o] * rsqrtf(var[o] + 1e-5f);
        scs[tid] = sc;
        bis[tid] = bet[o] - mean[o] * sc;
    }
    f32x4 acc[4];
#pragma unroll
    for (int i = 0; i < 4; ++i) acc[i] = (f32x4){0.f, 0.f, 0.f, 0.f};

    for (int kt = 0; kt < 9; ++kt) {
        int dy = kt / 3 - 1, dx = kt % 3 - 1;
        const unsigned short* src = inh + (size_t)(hrow + dy + 1) * SH + (pc0 + pxl + dx + 1);
        const unsigned short* wk  = wTh + (size_t)kt * 65536 + (size_t)o0 * 256;
        for (int ks = 0; ks < 256; ks += 32) {
            __syncthreads();
            unsigned short pk[4];
#pragma unroll
            for (int e = 0; e < 4; ++e) {
                int c = ks + (cg << 2) + e;
                pk[e] = src[(size_t)c * PSH];
            }
            *(short4*)&Bs[pxl][cg << 2] = *(short4*)pk;
            __syncthreads();
            bf16x8 af[4], bfr;
#pragma unroll
            for (int mi = 0; mi < 4; ++mi) {
                int o = (wr << 6) + (mi << 4) + lr;
                af[mi] = *(const bf16x8*)(wk + (size_t)o * 256 + ks + (lg << 3));
            }
            {
                int n = (wc << 4) + lr;
                bfr = *(const bf16x8*)(&Bs[n][lg << 3]);
            }
#pragma unroll
            for (int mi = 0; mi < 4; ++mi)
                acc[mi] = __builtin_amdgcn_mfma_f32_16x16x32_bf16(
                    af[mi], bfr, acc[mi], 0, 0, 0);
        }
    }
    size_t rowb = (size_t)(hrow + 1) * SH;
#pragma unroll
    for (int mi = 0; mi < 4; ++mi)
#pragma unroll
        for (int r = 0; r < 4; ++r) {
            int ol  = (wr << 6) + (mi << 4) + (lg << 2) + r;
            int o   = o0 + ol;
            int pxx = pc0 + (wc << 4) + lr;
            float rv = fmaxf(acc[mi][r] * scs[ol] + bis[ol], 0.0f);
            out_flat[(size_t)o * HW + (hrow << 7) + pxx] = rv;
            if (out_padh)
                out_padh[(size_t)o * PSH + rowb + pxx + 1] = f2bf(rv);
        }
}

extern "C" void kernel_launch(void* const* d_in, const int* in_sizes, int n_in,
                              void* d_out, int out_size, void* d_ws, size_t ws_size,
                              hipStream_t stream) {
    const float* x     = (const float*)d_in[0];
    const float* llf   = (const float*)d_in[1];
    const float* fm_w  = (const float*)d_in[2];
    const float* fs_w  = (const float*)d_in[3];
    const float* p_w   = (const float*)d_in[4];
    const float* p_b   = (const float*)d_in[5];
    const float* dc_w  = (const float*)d_in[6];
    const float* lc1_w = (const float*)d_in[7];
    const float* bn1g  = (const float*)d_in[8];
    const float* bn1b  = (const float*)d_in[9];
    const float* bn1m  = (const float*)d_in[10];
    const float* bn1v  = (const float*)d_in[11];
    const float* lc2_w = (const float*)d_in[12];
    const float* bn2g  = (const float*)d_in[13];
    const float* bn2b  = (const float*)d_in[14];
    const float* bn2m  = (const float*)d_in[15];
    const float* bn2v  = (const float*)d_in[16];
    float* out1 = (float*)d_out;
    float* out2 = out1 + (size_t)256 * HW;

    if (ws_size < 68960256u) return;
    char* ws = (char*)d_ws;
    // R0 [0, 34,611,200): ccpad f32 (dead after cvt) -> pbuf @0 (8.39MB, dead
    //   after make_idx) -> famh @0 (8.79MB), up1h @9,000,000 (8.79MB),
    //   P2 @17,825,792 (16.78MB; ends 34,603,008)
    float*          ccpad = (float*)ws;
    float*          pbuf  = (float*)ws;
    unsigned short* famh  = (unsigned short*)ws;
    unsigned short* up1h  = (unsigned short*)(ws + 9000000);
    float*          P2    = (float*)(ws + 17825792);
    // fam partials P0/P1 live in d_out (scratch until the convs overwrite it)
    float*          P0    = out1;                 // 16,777,216 B
    float*          P1    = out1 + (size_t)4194304;
    // R1 [34,611,200, +17,571,840): v f32 (dead after u_matmul) -> cch bf16
    float*          vbuf  = (float*)(ws + 34611200);
    unsigned short* cch   = (unsigned short*)(ws + 34611200);
    // R2 [52,183,040, +16,777,216): u f32 (dead after Cf) -> small tensors
    char* R2 = ws + 52183040;
    float*          ubuf   = (float*)R2;
    int4*           IDX    = (int4*)  (R2);                     // 2,359,296
    float4*         WT     = (float4*)(R2 + 2359296);           // 2,359,296
    unsigned short* dcwTh  = (unsigned short*)(R2 + 4718592);   // 2,359,296
    unsigned short* lcw1Th = (unsigned short*)(R2 + 7077888);   // 1,179,648
    unsigned short* lcw2Th = (unsigned short*)(R2 + 8257536);   // 1,179,648
    unsigned short* pwTh   = (unsigned short*)(R2 + 9437184);   //   294,912

    zero_ring_k<<<dim3(516), 256, 0, stream>>>(ccpad + (size_t)256 * PS, 256);
    upsample_k<<<dim3(67, 256), 256, 0, stream>>>(x, ccpad);
    gemm1x1_sig_k<<<dim3(16, 32), 256, 0, stream>>>(fm_w, llf, vbuf);
    u_matmul_k<<<dim3(2, 256), 256, 0, stream>>>(llf, vbuf, ubuf);
    gemm1x1_pad_k<<<dim3(16, 32), 256, 0, stream>>>(fs_w, ubuf, ccpad + (size_t)256 * PS);
    cvt_bf16_k<<<dim3(33800), 256, 0, stream>>>(ccpad, cch);   // v, u dead now
    tr_ocK_k<<<dim3(4608), 256, 0, stream>>>(dc_w, dcwTh, 512);
    tr_ocK_k<<<dim3(2304), 256, 0, stream>>>(lc1_w, lcw1Th, 256);
    tr_ocK_k<<<dim3(2304), 256, 0, stream>>>(lc2_w, lcw2Th, 256);
    tr_pw_k<<<dim3(576), 256, 0, stream>>>(p_w, pwTh);
    off_part_k<<<dim3(512), 256, 0, stream>>>(cch, pwTh, pbuf);     // ccpad dead
    make_idx_k<<<dim3(576), 256, 0, stream>>>(pbuf, p_b, IDX, WT);
    zero_ring_h_k<<<dim3(521), 256, 0, stream>>>(famh, 256);        // pbuf dead
    zero_ring_h_k<<<dim3(521), 256, 0, stream>>>(up1h, 256);
    fam3_k<<<dim3(1536), 256, 0, stream>>>(cch, dcwTh, IDX, WT, P0, P1, P2);
    fam_reduce_k<<<dim3(16384), 256, 0, stream>>>(P0, P1, P2, cch, famh);
    conv3_k<<<dim3(1024), 256, 0, stream>>>(famh, lcw1Th, bn1g, bn1b, bn1m, bn1v,
                                            out1, up1h);
    conv3_k<<<dim3(1024), 256, 0, stream>>>(up1h, lcw2Th, bn2g, bn2b, bn2m, bn2v,
                                            out2, nullptr);
}

// Round 6
// 758.494 us; speedup vs baseline: 1.4146x; 1.4146x over previous
//
#include <hip/hip_runtime.h>
#include <math.h>

#define HW   16384           // 128*128
#define PS   16900           // 130*130 f32 padded plane
#define PSH  17160           // 130*132 bf16 padded plane (stride 132)
#define SH   132

typedef __attribute__((ext_vector_type(8))) short bf16x8;
typedef __attribute__((ext_vector_type(4))) float f32x4;

__device__ inline unsigned short f2bf(float x) {
    unsigned int u = __float_as_uint(x);
    unsigned int r = (u + 0x7fffu + ((u >> 16) & 1u)) >> 16;
    return (unsigned short)r;
}
__device__ inline float bf2f(unsigned short h) {
    return __uint_as_float(((unsigned int)h) << 16);
}

// ---- zero the pad ring of nch f32 padded planes (stride 130) ---------------
__global__ __launch_bounds__(256) void zero_ring_k(float* __restrict__ base, int nch) {
    int t = blockIdx.x * 256 + threadIdx.x;
    if (t >= nch * 516) return;
    int ch = t / 516, rp = t - ch * 516;
    int row, col;
    if (rp < 130)      { row = 0;   col = rp; }
    else if (rp < 260) { row = 129; col = rp - 130; }
    else { int rem = rp - 260; row = 1 + (rem >> 1); col = (rem & 1) ? 129 : 0; }
    base[(size_t)ch * PS + row * 130 + col] = 0.0f;
}

// ---- zero the pad ring of nch bf16 padded planes (stride 132) --------------
__global__ __launch_bounds__(256) void zero_ring_h_k(unsigned short* __restrict__ base, int nch) {
    int t = blockIdx.x * 256 + threadIdx.x;
    if (t >= nch * 520) return;
    int ch = t / 520, rp = t - ch * 520;
    int row, col;
    if (rp < 132)      { row = 0;   col = rp; }
    else if (rp < 264) { row = 129; col = rp - 132; }
    else { int rem = rp - 264; row = 1 + (rem >> 1); col = (rem & 1) ? 129 : 0; }
    base[(size_t)ch * PSH + row * SH + col] = 0;
}

// ---- bilinear upsample (align_corners) 32x32 -> 128x128, into padded cc ----
__global__ __launch_bounds__(256) void upsample_k(const float* __restrict__ x,
                                                  float* __restrict__ ccpad) {
    int c = blockIdx.y;
    int idx = blockIdx.x * 256 + threadIdx.x;
    if (idx >= PS) return;
    int r = idx / 130, s = idx - r * 130;
    float val = 0.0f;
    if (r >= 1 && r <= 128 && s >= 1 && s <= 128) {
        int i = r - 1, j = s - 1;
        float yf = (float)i * (31.0f / 127.0f);
        float xf = (float)j * (31.0f / 127.0f);
        int y0 = min((int)yf, 31); int y1 = min(y0 + 1, 31);
        int x0 = min((int)xf, 31); int x1 = min(x0 + 1, 31);
        float wy = yf - (float)y0, wx = xf - (float)x0;
        const float* xc = x + (size_t)c * 1024;
        float a = xc[y0 * 32 + x0] * (1.0f - wx) + xc[y0 * 32 + x1] * wx;
        float b = xc[y1 * 32 + x0] * (1.0f - wx) + xc[y1 * 32 + x1] * wx;
        val = a * (1.0f - wy) + b * wy;
    }
    ccpad[(size_t)c * PS + idx] = val;
}

// ---- 1x1 conv GEMM + sigmoid ----------------------------------------------
__global__ __launch_bounds__(256) void gemm1x1_sig_k(const float* __restrict__ wmat,
                                                     const float* __restrict__ in,
                                                     float* __restrict__ out) {
    __shared__ float wl[2048];
    int tid = threadIdx.x;
    int o0 = blockIdx.y << 3;
    for (int i = tid; i < 2048; i += 256) wl[i] = wmat[(o0 << 8) + i];
    __syncthreads();
    int p = (blockIdx.x << 10) + (tid << 2);
    float4 acc[8];
#pragma unroll
    for (int j = 0; j < 8; ++j) acc[j] = make_float4(0.f, 0.f, 0.f, 0.f);
    for (int c = 0; c < 256; ++c) {
        float4 z = *(const float4*)(in + (size_t)c * HW + p);
#pragma unroll
        for (int j = 0; j < 8; ++j) {
            float wj = wl[(j << 8) + c];
            acc[j].x += wj * z.x; acc[j].y += wj * z.y;
            acc[j].z += wj * z.z; acc[j].w += wj * z.w;
        }
    }
#pragma unroll
    for (int j = 0; j < 8; ++j) {
        float4 r;
        r.x = 1.0f / (1.0f + expf(-acc[j].x));
        r.y = 1.0f / (1.0f + expf(-acc[j].y));
        r.z = 1.0f / (1.0f + expf(-acc[j].z));
        r.w = 1.0f / (1.0f + expf(-acc[j].w));
        *(float4*)(out + (size_t)(o0 + j) * HW + p) = r;
    }
}

// ---- 1x1 conv GEMM, writes into f32 padded planes (Cf -> ccpad hi) ---------
__global__ __launch_bounds__(256) void gemm1x1_pad_k(const float* __restrict__ wmat,
                                                     const float* __restrict__ in,
                                                     float* __restrict__ outpad) {
    __shared__ float wl[2048];
    int tid = threadIdx.x;
    int o0 = blockIdx.y << 3;
    for (int i = tid; i < 2048; i += 256) wl[i] = wmat[(o0 << 8) + i];
    __syncthreads();
    int p = (blockIdx.x << 10) + (tid << 2);
    float4 acc[8];
#pragma unroll
    for (int j = 0; j < 8; ++j) acc[j] = make_float4(0.f, 0.f, 0.f, 0.f);
    for (int c = 0; c < 256; ++c) {
        float4 z = *(const float4*)(in + (size_t)c * HW + p);
#pragma unroll
        for (int j = 0; j < 8; ++j) {
            float wj = wl[(j << 8) + c];
            acc[j].x += wj * z.x; acc[j].y += wj * z.y;
            acc[j].z += wj * z.z; acc[j].w += wj * z.w;
        }
    }
    int h = p >> 7, w = p & 127;
#pragma unroll
    for (int j = 0; j < 8; ++j) {
        float* dst = outpad + (size_t)(o0 + j) * PS + (h + 1) * 130 + (w + 1);
        dst[0] = acc[j].x; dst[1] = acc[j].y; dst[2] = acc[j].z; dst[3] = acc[j].w;
    }
}

// ---- u[c,h,w] = sum_k L[c,h,k]*v[c,k,w] + L[c,h,w] -------------------------
__global__ __launch_bounds__(256) void u_matmul_k(const float* __restrict__ llf,
                                                  const float* __restrict__ v,
                                                  float* __restrict__ u) {
    int c = blockIdx.y;
    const float* L = llf + (size_t)c * HW;
    const float* V = v   + (size_t)c * HW;
    float*       U = u   + (size_t)c * HW;
    int tid = threadIdx.x;
    int ty = tid >> 4, tx = tid & 15;
    int r0 = (blockIdx.x << 6) + (ty << 2);
    int w0 = tx << 3;
    float acc[4][8] = {};
    for (int k = 0; k < 128; ++k) {
        float a[4];
#pragma unroll
        for (int i = 0; i < 4; ++i) a[i] = L[(r0 + i) * 128 + k];
        float4 b0 = *(const float4*)(V + k * 128 + w0);
        float4 b1 = *(const float4*)(V + k * 128 + w0 + 4);
        float bv[8] = {b0.x, b0.y, b0.z, b0.w, b1.x, b1.y, b1.z, b1.w};
#pragma unroll
        for (int i = 0; i < 4; ++i)
#pragma unroll
            for (int j = 0; j < 8; ++j) acc[i][j] += a[i] * bv[j];
    }
#pragma unroll
    for (int i = 0; i < 4; ++i) {
#pragma unroll
        for (int j = 0; j < 8; ++j) acc[i][j] += L[(r0 + i) * 128 + w0 + j];
        *(float4*)(U + (r0 + i) * 128 + w0)     = make_float4(acc[i][0], acc[i][1], acc[i][2], acc[i][3]);
        *(float4*)(U + (r0 + i) * 128 + w0 + 4) = make_float4(acc[i][4], acc[i][5], acc[i][6], acc[i][7]);
    }
}

// ---- convert 512 f32 padded planes (stride 130) -> bf16 planes (stride 132)
__global__ __launch_bounds__(256) void cvt_bf16_k(const float* __restrict__ src,
                                                  unsigned short* __restrict__ dst) {
    int t = blockIdx.x * 256 + threadIdx.x;   // 512*16900 = 8,652,800 exactly
    int c = t / PS, r = t - c * PS;
    int row = r / 130, col = r - row * 130;
    dst[(size_t)c * PSH + row * SH + col] = f2bf(src[t]);
}

// ---- channel-major transpose: ccT[pix][c] = bf16(ccpad[c][pix]) ------------
__global__ __launch_bounds__(256) void cvtT_k(const float* __restrict__ src,
                                              unsigned short* __restrict__ dst) {
    int t = blockIdx.x * 256 + threadIdx.x;   // 130*130*512 = 8,652,800 exactly
    int c = t & 511, pix = t >> 9;
    dst[t] = f2bf(src[(size_t)c * PS + pix]);
}

// ---- weights (O,C,3,3) f32 -> [k][o][c] bf16 (O=256) -----------------------
__global__ __launch_bounds__(256) void tr_ocK_k(const float* __restrict__ w,
                                                unsigned short* __restrict__ dst, int C) {
    int t = blockIdx.x * 256 + threadIdx.x;
    if (t >= 9 * 256 * C) return;
    int c = t % C; int rest = t / C; int o = rest & 255; int k = rest >> 8;
    dst[t] = f2bf(w[(size_t)o * C * 9 + c * 9 + k]);
}

// ---- p_w (18,512,3,3) f32 -> [k][32][512] bf16, zero-padded to 32 o --------
__global__ __launch_bounds__(256) void tr_pw_k(const float* __restrict__ w,
                                               unsigned short* __restrict__ dst) {
    int t = blockIdx.x * 256 + threadIdx.x;
    if (t >= 9 * 32 * 512) return;
    int c = t & 511; int rest = t >> 9; int o = rest & 31; int k = rest >> 5;
    dst[t] = (o < 18) ? f2bf(w[(size_t)o * 4608 + c * 9 + k]) : (unsigned short)0;
}

// ============ offset conv 512->18: channel-split partials ===================
// grid 512: each block = 32o x 128px x 128ch partial -> pbuf[cg][32][HW] f32
__global__ __launch_bounds__(256, 2) void off_part_k(
        const unsigned short* __restrict__ cch,   // 512 bf16 planes PSH
        const unsigned short* __restrict__ pwTh,  // [9][32][512] bf16
        float* __restrict__ pbuf) {               // [4][32][HW] f32
    __shared__ __align__(16) unsigned short Bs[128][40];
    int b = blockIdx.x;
    int xcd = b & 7, slot = b >> 3;               // 64 slots
    int hrow = (xcd << 4) + (slot >> 2);
    int cg = slot & 3, c0 = cg << 7;
    int tid = threadIdx.x;
    int wv = tid >> 6, lane = tid & 63;
    int wr = wv >> 1, wc = wv & 1;                // o-half(16) x px-half(64)
    int lr = lane & 15, lg = lane >> 4;
    int px = tid & 127, sg = tid >> 7;
    f32x4 acc[4];
#pragma unroll
    for (int j = 0; j < 4; ++j) acc[j] = (f32x4){0.f, 0.f, 0.f, 0.f};

    for (int kt = 0; kt < 9; ++kt) {
        int dy = kt / 3 - 1, dx = kt % 3 - 1;
        const unsigned short* src = cch + (size_t)(hrow + dy + 1) * SH + (px + dx + 1);
        for (int ksl = 0; ksl < 128; ksl += 32) {
            __syncthreads();
#pragma unroll
            for (int q = 0; q < 4; ++q) {
                unsigned short pk[4];
#pragma unroll
                for (int e = 0; e < 4; ++e) {
                    int c = c0 + ksl + (sg << 4) + (q << 2) + e;
                    pk[e] = src[(size_t)c * PSH];
                }
                *(short4*)&Bs[px][(sg << 4) + (q << 2)] = *(short4*)pk;
            }
            __syncthreads();
            bf16x8 af, bfr[4];
            af = *(const bf16x8*)(pwTh + (size_t)kt * 16384
                                  + (size_t)((wr << 4) + lr) * 512 + c0 + ksl + (lg << 3));
#pragma unroll
            for (int ni = 0; ni < 4; ++ni) {
                int n = (wc << 6) + (ni << 4) + lr;
                bfr[ni] = *(const bf16x8*)(&Bs[n][lg << 3]);
            }
#pragma unroll
            for (int ni = 0; ni < 4; ++ni)
                acc[ni] = __builtin_amdgcn_mfma_f32_16x16x32_bf16(af, bfr[ni], acc[ni], 0, 0, 0);
        }
    }
#pragma unroll
    for (int ni = 0; ni < 4; ++ni)
#pragma unroll
        for (int r = 0; r < 4; ++r) {
            int o = (wr << 4) + (lg << 2) + r;
            int p = (hrow << 7) + (wc << 6) + (ni << 4) + lr;
            pbuf[(size_t)((cg << 5) + o) * HW + p] = acc[ni][r];
        }
}

// ---- per-(pixel,k): sum 4 partials; IDX = pixel-index*512 into ccT ---------
__global__ __launch_bounds__(256) void make_idx_k(const float* __restrict__ pbuf,
                                                  const float* __restrict__ pb,
                                                  int4* __restrict__ IDX,
                                                  float4* __restrict__ WT) {
    int t = blockIdx.x * 256 + threadIdx.x;
    if (t >= 9 * HW) return;
    int k = t >> 14, p = t & 16383;
    int h = p >> 7, w = p & 127;
    float ox = 0.f, oy = 0.f;
#pragma unroll
    for (int cg = 0; cg < 4; ++cg) {
        ox += pbuf[(size_t)((cg << 5) + k) * HW + p];
        oy += pbuf[(size_t)((cg << 5) + 9 + k) * HW + p];
    }
    float px = ox + pb[k]     + (float)(k / 3 - 1) + (float)(h + 1);
    float py = oy + pb[9 + k] + (float)(k % 3 - 1) + (float)(w + 1);
    float fx = floorf(px), fy = floorf(py);
    float x0 = fminf(fmaxf(fx,        0.f), 129.f);
    float x1 = fminf(fmaxf(fx + 1.0f, 0.f), 129.f);
    float y0 = fminf(fmaxf(fy,        0.f), 129.f);
    float y1 = fminf(fmaxf(fy + 1.0f, 0.f), 129.f);
    float pxc = fminf(fmaxf(px, 0.f), 129.f);
    float pyc = fminf(fmaxf(py, 0.f), 129.f);
    float gx0 = 1.0f + x0 - pxc, gx1 = 1.0f - x1 + pxc;
    float gy0 = 1.0f + y0 - pyc, gy1 = 1.0f - y1 + pyc;
    int ix0 = (int)x0, ix1 = (int)x1, iy0 = (int)y0, iy1 = (int)y1;
    IDX[t] = make_int4((ix0 * 130 + iy0) << 9, (ix1 * 130 + iy1) << 9,
                       (ix0 * 130 + iy1) << 9, (ix1 * 130 + iy0) << 9);
    WT[t]  = make_float4(gx0 * gy0, gx1 * gy1, gx0 * gy1, gx1 * gy0);
}

// ============ deformable contraction: channel-major 16B gathers =============
// 256o x 32px tiles, grid 512. Gather: 4 x dwordx4 per thread per 64-ch chunk
// (8x fewer gather instructions than plane-major scalar loads).
__global__ __launch_bounds__(256, 2) void fam4_k(
        const unsigned short* __restrict__ ccT,    // [130*130][512] bf16
        const unsigned short* __restrict__ cch,    // plane-major (Cf epilogue)
        const unsigned short* __restrict__ dcwTh,  // [9][256][512] bf16
        const int4* __restrict__ IDX, const float4* __restrict__ WT,
        unsigned short* __restrict__ famh) {       // 256 bf16 planes PSH
    __shared__ __align__(16) unsigned short Bs[32][72];   // 64 ch + 8 pad
    int b = blockIdx.x;
    int xcd = b & 7, sl = b >> 3;
    int nt = (xcd << 6) + sl;              // XCD owns 64 contiguous n-tiles
    int hrow = nt >> 2, pc0 = (nt & 3) << 5;
    int tid = threadIdx.x;
    int wv = tid >> 6, lane = tid & 63;
    int lr = lane & 15, lg = lane >> 4;
    int pxl = tid & 31, grp = tid >> 5;    // 8 groups x 8 channels = 64/chunk
    int p = (hrow << 7) + pc0 + pxl;
    f32x4 acc[4][2];
#pragma unroll
    for (int i = 0; i < 4; ++i)
#pragma unroll
        for (int j = 0; j < 2; ++j) acc[i][j] = (f32x4){0.f, 0.f, 0.f, 0.f};

    for (int kt = 0; kt < 9; ++kt) {
        int4   id = IDX[(kt << 14) + p];
        float4 wt = WT [(kt << 14) + p];
        const unsigned short* dwk = dcwTh + (size_t)kt * 131072;
        for (int ks = 0; ks < 512; ks += 64) {
            __syncthreads();
            {
                int cb = ks + (grp << 3);
                bf16x8 v0 = *(const bf16x8*)(ccT + id.x + cb);
                bf16x8 v1 = *(const bf16x8*)(ccT + id.y + cb);
                bf16x8 v2 = *(const bf16x8*)(ccT + id.z + cb);
                bf16x8 v3 = *(const bf16x8*)(ccT + id.w + cb);
                unsigned short pk[8];
#pragma unroll
                for (int e = 0; e < 8; ++e) {
                    float val = wt.x * bf2f((unsigned short)v0[e])
                              + wt.y * bf2f((unsigned short)v1[e])
                              + wt.z * bf2f((unsigned short)v2[e])
                              + wt.w * bf2f((unsigned short)v3[e]);
                    pk[e] = f2bf(val);
                }
                *(bf16x8*)&Bs[pxl][grp << 3] = *(bf16x8*)pk;
            }
            __syncthreads();
#pragma unroll
            for (int s = 0; s < 2; ++s) {
                int ko = ks + (s << 5) + (lg << 3);
                bf16x8 af[4], bfr[2];
#pragma unroll
                for (int mi = 0; mi < 4; ++mi) {
                    int o = (wv << 6) + (mi << 4) + lr;
                    af[mi] = *(const bf16x8*)(dwk + (size_t)o * 512 + ko);
                }
#pragma unroll
                for (int ni = 0; ni < 2; ++ni) {
                    int n = (ni << 4) + lr;
                    bfr[ni] = *(const bf16x8*)(&Bs[n][(s << 5) + (lg << 3)]);
                }
#pragma unroll
                for (int mi = 0; mi < 4; ++mi)
#pragma unroll
                    for (int ni = 0; ni < 2; ++ni)
                        acc[mi][ni] = __builtin_amdgcn_mfma_f32_16x16x32_bf16(
                            af[mi], bfr[ni], acc[mi][ni], 0, 0, 0);
            }
        }
    }
    size_t rowb = (size_t)(hrow + 1) * SH;
#pragma unroll
    for (int mi = 0; mi < 4; ++mi)
#pragma unroll
        for (int ni = 0; ni < 2; ++ni)
#pragma unroll
            for (int r = 0; r < 4; ++r) {
                int o   = (wv << 6) + (mi << 4) + (lg << 2) + r;
                int pxx = pc0 + (ni << 4) + lr;
                float cf = bf2f(cch[(size_t)(256 + o) * PSH + rowb + pxx + 1]);
                famh[(size_t)o * PSH + rowb + pxx + 1] = f2bf(acc[mi][ni][r] + cf);
            }
}

// ============ 3x3 conv 256->256: full-M 256o x 32px tiles + BN + ReLU =======
__global__ __launch_bounds__(256, 2) void conv2_k(
        const unsigned short* __restrict__ inh,   // 256 bf16 planes PSH, ring=0
        const unsigned short* __restrict__ wTh,   // [9][256][256] bf16
        const float* __restrict__ gam, const float* __restrict__ bet,
        const float* __restrict__ mean, const float* __restrict__ var,
        float* __restrict__ out_flat,             // [256][HW] f32
        unsigned short* __restrict__ out_padh) {  // optional bf16 planes
    __shared__ __align__(16) unsigned short Bs[32][40];
    __shared__ float scs[256], bis[256];
    int b = blockIdx.x;
    int xcd = b & 7, slot = b >> 3;
    int nt = (xcd << 6) + slot;
    int hrow = nt >> 2, pc0 = (nt & 3) << 5;
    int tid = threadIdx.x;
    int wv = tid >> 6, lane = tid & 63;
    int lr = lane & 15, lg = lane >> 4;
    int pxl = tid & 31, cg = tid >> 5;
    {
        float sc = gam[tid] * rsqrtf(var[tid] + 1e-5f);
        scs[tid] = sc;
        bis[tid] = bet[tid] - mean[tid] * sc;
    }
    f32x4 acc[4][2];
#pragma unroll
    for (int i = 0; i < 4; ++i)
#pragma unroll
        for (int j = 0; j < 2; ++j) acc[i][j] = (f32x4){0.f, 0.f, 0.f, 0.f};

    for (int kt = 0; kt < 9; ++kt) {
        int dy = kt / 3 - 1, dx = kt % 3 - 1;
        const unsigned short* src = inh + (size_t)(hrow + dy + 1) * SH + (pc0 + pxl + dx + 1);
        const unsigned short* wk  = wTh + (size_t)kt * 65536;
        for (int ks = 0; ks < 256; ks += 32) {
            __syncthreads();
            unsigned short pk[4];
#pragma unroll
            for (int e = 0; e < 4; ++e) {
                int c = ks + (cg << 2) + e;
                pk[e] = src[(size_t)c * PSH];
            }
            *(short4*)&Bs[pxl][cg << 2] = *(short4*)pk;
            __syncthreads();
            bf16x8 af[4], bfr[2];
#pragma unroll
            for (int mi = 0; mi < 4; ++mi) {
                int o = (wv << 6) + (mi << 4) + lr;
                af[mi] = *(const bf16x8*)(wk + (size_t)o * 256 + ks + (lg << 3));
            }
#pragma unroll
            for (int ni = 0; ni < 2; ++ni) {
                int n = (ni << 4) + lr;
                bfr[ni] = *(const bf16x8*)(&Bs[n][lg << 3]);
            }
#pragma unroll
            for (int mi = 0; mi < 4; ++mi)
#pragma unroll
                for (int ni = 0; ni < 2; ++ni)
                    acc[mi][ni] = __builtin_amdgcn_mfma_f32_16x16x32_bf16(
                        af[mi], bfr[ni], acc[mi][ni], 0, 0, 0);
        }
    }
    size_t rowb = (size_t)(hrow + 1) * SH;
#pragma unroll
    for (int mi = 0; mi < 4; ++mi)
#pragma unroll
        for (int ni = 0; ni < 2; ++ni)
#pragma unroll
            for (int r = 0; r < 4; ++r) {
                int o   = (wv << 6) + (mi << 4) + (lg << 2) + r;
                int pxx = pc0 + (ni << 4) + lr;
                float rv = fmaxf(acc[mi][ni][r] * scs[o] + bis[o], 0.0f);
                out_flat[(size_t)o * HW + (hrow << 7) + pxx] = rv;
                if (out_padh)
                    out_padh[(size_t)o * PSH + rowb + pxx + 1] = f2bf(rv);
            }
}

extern "C" void kernel_launch(void* const* d_in, const int* in_sizes, int n_in,
                              void* d_out, int out_size, void* d_ws, size_t ws_size,
                              hipStream_t stream) {
    const float* x     = (const float*)d_in[0];
    const float* llf   = (const float*)d_in[1];
    const float* fm_w  = (const float*)d_in[2];
    const float* fs_w  = (const float*)d_in[3];
    const float* p_w   = (const float*)d_in[4];
    const float* p_b   = (const float*)d_in[5];
    const float* dc_w  = (const float*)d_in[6];
    const float* lc1_w = (const float*)d_in[7];
    const float* bn1g  = (const float*)d_in[8];
    const float* bn1b  = (const float*)d_in[9];
    const float* bn1m  = (const float*)d_in[10];
    const float* bn1v  = (const float*)d_in[11];
    const float* lc2_w = (const float*)d_in[12];
    const float* bn2g  = (const float*)d_in[13];
    const float* bn2b  = (const float*)d_in[14];
    const float* bn2m  = (const float*)d_in[15];
    const float* bn2v  = (const float*)d_in[16];
    float* out1 = (float*)d_out;
    float* out2 = out1 + (size_t)256 * HW;

    if (ws_size < 68960256u) return;
    char* ws = (char*)d_ws;
    // R0 [0, 34,611,200): ccpad f32 (dead after cvtT) -> pbuf @0 (8.39MB, dead
    //   after make_idx) -> famh @0 (8.79MB), up1h @9,000,000 (8.79MB)
    float*          ccpad = (float*)ws;
    float*          pbuf  = (float*)ws;
    unsigned short* famh  = (unsigned short*)ws;
    unsigned short* up1h  = (unsigned short*)(ws + 9000000);
    // ccT (channel-major bf16, 17,305,600 B) lives in d_out: it is dead before
    // conv2_k writes out1 (fam4_k is the last reader, strictly earlier in-stream).
    unsigned short* ccT   = (unsigned short*)d_out;
    // R1 [34,611,200, +17,571,840): v f32 (dead after u_matmul) -> cch bf16
    float*          vbuf  = (float*)(ws + 34611200);
    unsigned short* cch   = (unsigned short*)(ws + 34611200);
    // R2 [52,183,040, +16,777,216): u f32 (dead after Cf) -> small tensors
    char* R2 = ws + 52183040;
    float*          ubuf   = (float*)R2;
    int4*           IDX    = (int4*)  (R2);                     // 2,359,296
    float4*         WT     = (float4*)(R2 + 2359296);           // 2,359,296
    unsigned short* dcwTh  = (unsigned short*)(R2 + 4718592);   // 2,359,296
    unsigned short* lcw1Th = (unsigned short*)(R2 + 7077888);   // 1,179,648
    unsigned short* lcw2Th = (unsigned short*)(R2 + 8257536);   // 1,179,648
    unsigned short* pwTh   = (unsigned short*)(R2 + 9437184);   //   294,912

    zero_ring_k<<<dim3(516), 256, 0, stream>>>(ccpad + (size_t)256 * PS, 256);
    upsample_k<<<dim3(67, 256), 256, 0, stream>>>(x, ccpad);
    gemm1x1_sig_k<<<dim3(16, 32), 256, 0, stream>>>(fm_w, llf, vbuf);
    u_matmul_k<<<dim3(2, 256), 256, 0, stream>>>(llf, vbuf, ubuf);
    gemm1x1_pad_k<<<dim3(16, 32), 256, 0, stream>>>(fs_w, ubuf, ccpad + (size_t)256 * PS);
    cvt_bf16_k<<<dim3(33800), 256, 0, stream>>>(ccpad, cch);   // v, u dead now
    cvtT_k<<<dim3(33800), 256, 0, stream>>>(ccpad, ccT);       // channel-major copy
    tr_ocK_k<<<dim3(4608), 256, 0, stream>>>(dc_w, dcwTh, 512);
    tr_ocK_k<<<dim3(2304), 256, 0, stream>>>(lc1_w, lcw1Th, 256);
    tr_ocK_k<<<dim3(2304), 256, 0, stream>>>(lc2_w, lcw2Th, 256);
    tr_pw_k<<<dim3(576), 256, 0, stream>>>(p_w, pwTh);
    off_part_k<<<dim3(512), 256, 0, stream>>>(cch, pwTh, pbuf);     // ccpad dead
    make_idx_k<<<dim3(576), 256, 0, stream>>>(pbuf, p_b, IDX, WT);
    zero_ring_h_k<<<dim3(521), 256, 0, stream>>>(famh, 256);        // pbuf dead
    zero_ring_h_k<<<dim3(521), 256, 0, stream>>>(up1h, 256);
    fam4_k<<<dim3(512), 256, 0, stream>>>(ccT, cch, dcwTh, IDX, WT, famh);
    conv2_k<<<dim3(512), 256, 0, stream>>>(famh, lcw1Th, bn1g, bn1b, bn1m, bn1v,
                                           out1, up1h);                 // ccT dead
    conv2_k<<<dim3(512), 256, 0, stream>>>(up1h, lcw2Th, bn2g, bn2b, bn2m, bn2v,
                                           out2, nullptr);
}

// Round 8
// 662.719 us; speedup vs baseline: 1.6190x; 1.1445x over previous
//
#include <hip/hip_runtime.h>
#include <math.h>

#define HW   16384           // 128*128
#define PS   16900           // 130*130 f32 padded plane
#define PSH  17160           // 130*132 bf16 padded plane (stride 132)
#define SH   132

typedef __attribute__((ext_vector_type(8))) short bf16x8;
typedef __attribute__((ext_vector_type(4))) float f32x4;

__device__ inline unsigned short f2bf(float x) {
    unsigned int u = __float_as_uint(x);
    unsigned int r = (u + 0x7fffu + ((u >> 16) & 1u)) >> 16;
    return (unsigned short)r;
}
__device__ inline float bf2f(unsigned short h) {
    return __uint_as_float(((unsigned int)h) << 16);
}

// ---- zero the pad ring of nch bf16 padded planes (stride 132) --------------
__global__ __launch_bounds__(256) void zero_ring_h_k(unsigned short* __restrict__ base, int nch) {
    int t = blockIdx.x * 256 + threadIdx.x;
    if (t >= nch * 520) return;
    int ch = t / 520, rp = t - ch * 520;
    int row, col;
    if (rp < 132)      { row = 0;   col = rp; }
    else if (rp < 264) { row = 129; col = rp - 132; }
    else {
        int rem = rp - 264;
        if (rem >= 256) return;            // rows 1..128 only (no OOB spill)
        row = 1 + (rem >> 1); col = (rem & 1) ? 129 : 0;
    }
    base[(size_t)ch * PSH + row * SH + col] = 0;
}

// ---- zero ccT ring pixels for channels 256..511 (Cf) -----------------------
__global__ __launch_bounds__(256) void ringT_k(unsigned short* __restrict__ ccT) {
    int t = blockIdx.x * 256 + threadIdx.x;
    if (t >= 520 * 256) return;
    int ci = t & 255, rp = t >> 8;
    int row, col;
    if (rp < 130)      { row = 0;   col = rp; }
    else if (rp < 260) { row = 129; col = rp - 130; }
    else {
        int rem = rp - 260;
        if (rem >= 256) return;            // rows 1..128 only (no OOB spill)
        row = 1 + (rem >> 1); col = (rem & 1) ? 129 : 0;
    }
    ccT[(size_t)(row * 130 + col) * 512 + 256 + ci] = 0;
}

// ---- bilinear upsample (align_corners) 32x32 -> 128x128, into 256 f32 planes
__global__ __launch_bounds__(256) void upsample_k(const float* __restrict__ x,
                                                  float* __restrict__ ccpad) {
    int c = blockIdx.y;
    int idx = blockIdx.x * 256 + threadIdx.x;
    if (idx >= PS) return;
    int r = idx / 130, s = idx - r * 130;
    float val = 0.0f;
    if (r >= 1 && r <= 128 && s >= 1 && s <= 128) {
        int i = r - 1, j = s - 1;
        float yf = (float)i * (31.0f / 127.0f);
        float xf = (float)j * (31.0f / 127.0f);
        int y0 = min((int)yf, 31); int y1 = min(y0 + 1, 31);
        int x0 = min((int)xf, 31); int x1 = min(x0 + 1, 31);
        float wy = yf - (float)y0, wx = xf - (float)x0;
        const float* xc = x + (size_t)c * 1024;
        float a = xc[y0 * 32 + x0] * (1.0f - wx) + xc[y0 * 32 + x1] * wx;
        float b = xc[y1 * 32 + x0] * (1.0f - wx) + xc[y1 * 32 + x1] * wx;
        val = a * (1.0f - wy) + b * wy;
    }
    ccpad[(size_t)c * PS + idx] = val;
}

// ---- flat transpose+cvt: src f32 [256][npx] -> dst bf16 [npx][256] ---------
__global__ __launch_bounds__(256) void cvtT_flat_k(const float* __restrict__ src,
                                                   unsigned short* __restrict__ dst,
                                                   int npx) {
    int t = blockIdx.x * 256 + threadIdx.x;    // (pix, c), c fastest
    int c = t & 255, pix = t >> 8;
    dst[t] = f2bf(src[(size_t)c * npx + pix]);
}

// ---- ccpad f32 planes (256 ch, stride 130) -> ccT[pix][512] ch 0..255 ------
__global__ __launch_bounds__(256) void cvtT_k(const float* __restrict__ src,
                                              unsigned short* __restrict__ dst) {
    int t = blockIdx.x * 256 + threadIdx.x;    // 130*130*256 exactly
    int c = t & 255, pix = t >> 8;
    dst[(size_t)pix * 512 + c] = f2bf(src[(size_t)c * PS + pix]);
}

// ---- fm_w / fs_w (256x256 f32) -> bf16 -------------------------------------
__global__ __launch_bounds__(256) void w2bf_k(const float* __restrict__ a,
                                              const float* __restrict__ b,
                                              unsigned short* __restrict__ da,
                                              unsigned short* __restrict__ db) {
    int t = blockIdx.x * 256 + threadIdx.x;
    if (t >= 65536) return;
    da[t] = f2bf(a[t]);
    db[t] = f2bf(b[t]);
}

// ---- u[c,h,w] = sum_k L[c,h,k]*v[c,k,w] + L[c,h,w] (f32) -------------------
__global__ __launch_bounds__(256) void u_matmul_k(const float* __restrict__ llf,
                                                  const float* __restrict__ v,
                                                  float* __restrict__ u) {
    int c = blockIdx.y;
    const float* L = llf + (size_t)c * HW;
    const float* V = v   + (size_t)c * HW;
    float*       U = u   + (size_t)c * HW;
    int tid = threadIdx.x;
    int ty = tid >> 4, tx = tid & 15;
    int r0 = (blockIdx.x << 6) + (ty << 2);
    int w0 = tx << 3;
    float acc[4][8] = {};
    for (int k = 0; k < 128; ++k) {
        float a[4];
#pragma unroll
        for (int i = 0; i < 4; ++i) a[i] = L[(r0 + i) * 128 + k];
        float4 b0 = *(const float4*)(V + k * 128 + w0);
        float4 b1 = *(const float4*)(V + k * 128 + w0 + 4);
        float bv[8] = {b0.x, b0.y, b0.z, b0.w, b1.x, b1.y, b1.z, b1.w};
#pragma unroll
        for (int i = 0; i < 4; ++i)
#pragma unroll
            for (int j = 0; j < 8; ++j) acc[i][j] += a[i] * bv[j];
    }
#pragma unroll
    for (int i = 0; i < 4; ++i) {
#pragma unroll
        for (int j = 0; j < 8; ++j) acc[i][j] += L[(r0 + i) * 128 + w0 + j];
        *(float4*)(U + (r0 + i) * 128 + w0)     = make_float4(acc[i][0], acc[i][1], acc[i][2], acc[i][3]);
        *(float4*)(U + (r0 + i) * 128 + w0 + 4) = make_float4(acc[i][4], acc[i][5], acc[i][6], acc[i][7]);
    }
}

// ---- weights (O,C,3,3) f32 -> [k][o][c] bf16 (O=256) -----------------------
__global__ __launch_bounds__(256) void tr_ocK_k(const float* __restrict__ w,
                                                unsigned short* __restrict__ dst, int C) {
    int t = blockIdx.x * 256 + threadIdx.x;
    if (t >= 9 * 256 * C) return;
    int c = t % C; int rest = t / C; int o = rest & 255; int k = rest >> 8;
    dst[t] = f2bf(w[(size_t)o * C * 9 + c * 9 + k]);
}

// ---- p_w (18,512,3,3) f32 -> [k][32][512] bf16, zero-padded to 32 o --------
__global__ __launch_bounds__(256) void tr_pw_k(const float* __restrict__ w,
                                               unsigned short* __restrict__ dst) {
    int t = blockIdx.x * 256 + threadIdx.x;
    if (t >= 9 * 32 * 512) return;
    int c = t & 511; int rest = t >> 9; int o = rest & 31; int k = rest >> 5;
    dst[t] = (o < 18) ? f2bf(w[(size_t)o * 4608 + c * 9 + k]) : (unsigned short)0;
}

// ============ 1x1 GEMM (K=256) 256o x 32px MFMA + sigmoid -> f32 planes =====
__global__ __launch_bounds__(256, 2) void vmfma_k(
        const unsigned short* __restrict__ inT,   // [HW][256] bf16
        const unsigned short* __restrict__ wh,    // [256][256] bf16
        float* __restrict__ vout) {               // [256][HW] f32
    __shared__ __align__(16) unsigned short Bs[32][72];
    int b = blockIdx.x;
    int xcd = b & 7, sl = b >> 3;
    int nt = (xcd << 6) + sl;
    int hrow = nt >> 2, pc0 = (nt & 3) << 5;
    int tid = threadIdx.x;
    int wv = tid >> 6, lane = tid & 63;
    int lr = lane & 15, lg = lane >> 4;
    int pxl = tid & 31, grp = tid >> 5;
    int p = (hrow << 7) + pc0 + pxl;
    f32x4 acc[4][2];
#pragma unroll
    for (int i = 0; i < 4; ++i)
#pragma unroll
        for (int j = 0; j < 2; ++j) acc[i][j] = (f32x4){0.f, 0.f, 0.f, 0.f};
    for (int ks = 0; ks < 256; ks += 64) {
        __syncthreads();
        *(bf16x8*)&Bs[pxl][grp << 3] =
            *(const bf16x8*)(inT + (size_t)p * 256 + ks + (grp << 3));
        __syncthreads();
#pragma unroll
        for (int s = 0; s < 2; ++s) {
            int ko = ks + (s << 5) + (lg << 3);
            bf16x8 af[4], bfr[2];
#pragma unroll
            for (int mi = 0; mi < 4; ++mi)
                af[mi] = *(const bf16x8*)(wh + (size_t)((wv << 6) + (mi << 4) + lr) * 256 + ko);
#pragma unroll
            for (int ni = 0; ni < 2; ++ni)
                bfr[ni] = *(const bf16x8*)(&Bs[(ni << 4) + lr][(s << 5) + (lg << 3)]);
#pragma unroll
            for (int mi = 0; mi < 4; ++mi)
#pragma unroll
                for (int ni = 0; ni < 2; ++ni)
                    acc[mi][ni] = __builtin_amdgcn_mfma_f32_16x16x32_bf16(
                        af[mi], bfr[ni], acc[mi][ni], 0, 0, 0);
        }
    }
#pragma unroll
    for (int mi = 0; mi < 4; ++mi)
#pragma unroll
        for (int ni = 0; ni < 2; ++ni)
#pragma unroll
            for (int r = 0; r < 4; ++r) {
                int o   = (wv << 6) + (mi << 4) + (lg << 2) + r;
                int pxx = pc0 + (ni << 4) + lr;
                vout[(size_t)o * HW + (hrow << 7) + pxx] =
                    1.0f / (1.0f + expf(-acc[mi][ni][r]));
            }
}

// ============ 1x1 GEMM (K=256) Cf -> ccT channels 256..511 ==================
__global__ __launch_bounds__(256, 2) void cfmfma_k(
        const unsigned short* __restrict__ inT,   // uT [HW][256] bf16
        const unsigned short* __restrict__ wh,    // fs_w [256][256] bf16
        unsigned short* __restrict__ ccT) {       // [130*130][512] bf16
    __shared__ __align__(16) unsigned short Bs[32][72];
    int b = blockIdx.x;
    int xcd = b & 7, sl = b >> 3;
    int nt = (xcd << 6) + sl;
    int hrow = nt >> 2, pc0 = (nt & 3) << 5;
    int tid = threadIdx.x;
    int wv = tid >> 6, lane = tid & 63;
    int lr = lane & 15, lg = lane >> 4;
    int pxl = tid & 31, grp = tid >> 5;
    int p = (hrow << 7) + pc0 + pxl;
    f32x4 acc[4][2];
#pragma unroll
    for (int i = 0; i < 4; ++i)
#pragma unroll
        for (int j = 0; j < 2; ++j) acc[i][j] = (f32x4){0.f, 0.f, 0.f, 0.f};
    for (int ks = 0; ks < 256; ks += 64) {
        __syncthreads();
        *(bf16x8*)&Bs[pxl][grp << 3] =
            *(const bf16x8*)(inT + (size_t)p * 256 + ks + (grp << 3));
        __syncthreads();
#pragma unroll
        for (int s = 0; s < 2; ++s) {
            int ko = ks + (s << 5) + (lg << 3);
            bf16x8 af[4], bfr[2];
#pragma unroll
            for (int mi = 0; mi < 4; ++mi)
                af[mi] = *(const bf16x8*)(wh + (size_t)((wv << 6) + (mi << 4) + lr) * 256 + ko);
#pragma unroll
            for (int ni = 0; ni < 2; ++ni)
                bfr[ni] = *(const bf16x8*)(&Bs[(ni << 4) + lr][(s << 5) + (lg << 3)]);
#pragma unroll
            for (int mi = 0; mi < 4; ++mi)
#pragma unroll
                for (int ni = 0; ni < 2; ++ni)
                    acc[mi][ni] = __builtin_amdgcn_mfma_f32_16x16x32_bf16(
                        af[mi], bfr[ni], acc[mi][ni], 0, 0, 0);
        }
    }
#pragma unroll
    for (int mi = 0; mi < 4; ++mi)
#pragma unroll
        for (int ni = 0; ni < 2; ++ni) {
            int pxx = pc0 + (ni << 4) + lr;
            int pix = (hrow + 1) * 130 + pxx + 1;
            unsigned short pk[4];
#pragma unroll
            for (int r = 0; r < 4; ++r) pk[r] = f2bf(acc[mi][ni][r]);
            *(ushort4*)(ccT + (size_t)pix * 512 + 256 + (wv << 6) + (mi << 4) + (lg << 2))
                = *(ushort4*)pk;
        }
}

// ============ offset conv 512->18: channel-split partials, ccT staging ======
__global__ __launch_bounds__(256, 2) void off_part_k(
        const unsigned short* __restrict__ ccT,   // [130*130][512] bf16
        const unsigned short* __restrict__ pwTh,  // [9][32][512] bf16
        float* __restrict__ pbuf) {               // [4][32][HW] f32
    __shared__ __align__(16) unsigned short Bs[128][40];
    int b = blockIdx.x;
    int xcd = b & 7, slot = b >> 3;               // 64 slots
    int hrow = (xcd << 4) + (slot >> 2);
    int cg = slot & 3, c0 = cg << 7;
    int tid = threadIdx.x;
    int wv = tid >> 6, lane = tid & 63;
    int wr = wv >> 1, wc = wv & 1;                // o-half(16) x px-half(64)
    int lr = lane & 15, lg = lane >> 4;
    int px = tid & 127, sg = tid >> 7;            // sg in 0..1
    f32x4 acc[4];
#pragma unroll
    for (int j = 0; j < 4; ++j) acc[j] = (f32x4){0.f, 0.f, 0.f, 0.f};

    for (int kt = 0; kt < 9; ++kt) {
        int dy = kt / 3 - 1, dx = kt % 3 - 1;
        int pixb = (hrow + dy + 1) * 130 + dx + 1;
        for (int ksl = 0; ksl < 128; ksl += 32) {
            __syncthreads();
#pragma unroll
            for (int q = 0; q < 2; ++q) {
                int cofs = (q << 4) + (sg << 3);
                *(bf16x8*)&Bs[px][cofs] =
                    *(const bf16x8*)(ccT + (size_t)(pixb + px) * 512 + c0 + ksl + cofs);
            }
            __syncthreads();
            bf16x8 af, bfr[4];
            af = *(const bf16x8*)(pwTh + (size_t)kt * 16384
                                  + (size_t)((wr << 4) + lr) * 512 + c0 + ksl + (lg << 3));
#pragma unroll
            for (int ni = 0; ni < 4; ++ni) {
                int n = (wc << 6) + (ni << 4) + lr;
                bfr[ni] = *(const bf16x8*)(&Bs[n][lg << 3]);
            }
#pragma unroll
            for (int ni = 0; ni < 4; ++ni)
                acc[ni] = __builtin_amdgcn_mfma_f32_16x16x32_bf16(af, bfr[ni], acc[ni], 0, 0, 0);
        }
    }
#pragma unroll
    for (int ni = 0; ni < 4; ++ni)
#pragma unroll
        for (int r = 0; r < 4; ++r) {
            int o = (wr << 4) + (lg << 2) + r;
            int p = (hrow << 7) + (wc << 6) + (ni << 4) + lr;
            pbuf[(size_t)((cg << 5) + o) * HW + p] = acc[ni][r];
        }
}

// ---- per-(pixel,k): sum 4 partials; IDX = pixel-index*512 into ccT ---------
__global__ __launch_bounds__(256) void make_idx_k(const float* __restrict__ pbuf,
                                                  const float* __restrict__ pb,
                                                  int4* __restrict__ IDX,
                                                  float4* __restrict__ WT) {
    int t = blockIdx.x * 256 + threadIdx.x;
    if (t >= 9 * HW) return;
    int k = t >> 14, p = t & 16383;
    int h = p >> 7, w = p & 127;
    float ox = 0.f, oy = 0.f;
#pragma unroll
    for (int cg = 0; cg < 4; ++cg) {
        ox += pbuf[(size_t)((cg << 5) + k) * HW + p];
        oy += pbuf[(size_t)((cg << 5) + 9 + k) * HW + p];
    }
    float px = ox + pb[k]     + (float)(k / 3 - 1) + (float)(h + 1);
    float py = oy + pb[9 + k] + (float)(k % 3 - 1) + (float)(w + 1);
    float fx = floorf(px), fy = floorf(py);
    float x0 = fminf(fmaxf(fx,        0.f), 129.f);
    float x1 = fminf(fmaxf(fx + 1.0f, 0.f), 129.f);
    float y0 = fminf(fmaxf(fy,        0.f), 129.f);
    float y1 = fminf(fmaxf(fy + 1.0f, 0.f), 129.f);
    float pxc = fminf(fmaxf(px, 0.f), 129.f);
    float pyc = fminf(fmaxf(py, 0.f), 129.f);
    float gx0 = 1.0f + x0 - pxc, gx1 = 1.0f - x1 + pxc;
    float gy0 = 1.0f + y0 - pyc, gy1 = 1.0f - y1 + pyc;
    int ix0 = (int)x0, ix1 = (int)x1, iy0 = (int)y0, iy1 = (int)y1;
    IDX[t] = make_int4((ix0 * 130 + iy0) << 9, (ix1 * 130 + iy1) << 9,
                       (ix0 * 130 + iy1) << 9, (ix1 * 130 + iy0) << 9);
    WT[t]  = make_float4(gx0 * gy0, gx1 * gy1, gx0 * gy1, gx1 * gy0);
}

// ============ deformable contraction: channel-major 16B gathers =============
__global__ __launch_bounds__(256, 2) void fam4_k(
        const unsigned short* __restrict__ ccT,    // [130*130][512] bf16
        const unsigned short* __restrict__ dcwTh,  // [9][256][512] bf16
        const int4* __restrict__ IDX, const float4* __restrict__ WT,
        unsigned short* __restrict__ famh) {       // 256 bf16 planes PSH
    __shared__ __align__(16) unsigned short Bs[32][72];   // 64 ch + 8 pad
    int b = blockIdx.x;
    int xcd = b & 7, sl = b >> 3;
    int nt = (xcd << 6) + sl;
    int hrow = nt >> 2, pc0 = (nt & 3) << 5;
    int tid = threadIdx.x;
    int wv = tid >> 6, lane = tid & 63;
    int lr = lane & 15, lg = lane >> 4;
    int pxl = tid & 31, grp = tid >> 5;
    int p = (hrow << 7) + pc0 + pxl;
    f32x4 acc[4][2];
#pragma unroll
    for (int i = 0; i < 4; ++i)
#pragma unroll
        for (int j = 0; j < 2; ++j) acc[i][j] = (f32x4){0.f, 0.f, 0.f, 0.f};

    for (int kt = 0; kt < 9; ++kt) {
        int4   id = IDX[(kt << 14) + p];
        float4 wt = WT [(kt << 14) + p];
        const unsigned short* dwk = dcwTh + (size_t)kt * 131072;
        for (int ks = 0; ks < 512; ks += 64) {
            __syncthreads();
            {
                int cb = ks + (grp << 3);
                bf16x8 v0 = *(const bf16x8*)(ccT + id.x + cb);
                bf16x8 v1 = *(const bf16x8*)(ccT + id.y + cb);
                bf16x8 v2 = *(const bf16x8*)(ccT + id.z + cb);
                bf16x8 v3 = *(const bf16x8*)(ccT + id.w + cb);
                unsigned short pk[8];
#pragma unroll
                for (int e = 0; e < 8; ++e) {
                    float val = wt.x * bf2f((unsigned short)v0[e])
                              + wt.y * bf2f((unsigned short)v1[e])
                              + wt.z * bf2f((unsigned short)v2[e])
                              + wt.w * bf2f((unsigned short)v3[e]);
                    pk[e] = f2bf(val);
                }
                *(bf16x8*)&Bs[pxl][grp << 3] = *(bf16x8*)pk;
            }
            __syncthreads();
#pragma unroll
            for (int s = 0; s < 2; ++s) {
                int ko = ks + (s << 5) + (lg << 3);
                bf16x8 af[4], bfr[2];
#pragma unroll
                for (int mi = 0; mi < 4; ++mi) {
                    int o = (wv << 6) + (mi << 4) + lr;
                    af[mi] = *(const bf16x8*)(dwk + (size_t)o * 512 + ko);
                }
#pragma unroll
                for (int ni = 0; ni < 2; ++ni) {
                    int n = (ni << 4) + lr;
                    bfr[ni] = *(const bf16x8*)(&Bs[n][(s << 5) + (lg << 3)]);
                }
#pragma unroll
                for (int mi = 0; mi < 4; ++mi)
#pragma unroll
                    for (int ni = 0; ni < 2; ++ni)
                        acc[mi][ni] = __builtin_amdgcn_mfma_f32_16x16x32_bf16(
                            af[mi], bfr[ni], acc[mi][ni], 0, 0, 0);
            }
        }
    }
    size_t rowb = (size_t)(hrow + 1) * SH;
#pragma unroll
    for (int mi = 0; mi < 4; ++mi)
#pragma unroll
        for (int ni = 0; ni < 2; ++ni)
#pragma unroll
            for (int r = 0; r < 4; ++r) {
                int o   = (wv << 6) + (mi << 4) + (lg << 2) + r;
                int pxx = pc0 + (ni << 4) + lr;
                float cf = bf2f(ccT[(size_t)((hrow + 1) * 130 + pxx + 1) * 512 + 256 + o]);
                famh[(size_t)o * PSH + rowb + pxx + 1] = f2bf(acc[mi][ni][r] + cf);
            }
}

// ============ 3x3 conv 256->256: full-M 256o x 32px tiles + BN + ReLU =======
__global__ __launch_bounds__(256, 2) void conv2_k(
        const unsigned short* __restrict__ inh,   // 256 bf16 planes PSH, ring=0
        const unsigned short* __restrict__ wTh,   // [9][256][256] bf16
        const float* __restrict__ gam, const float* __restrict__ bet,
        const float* __restrict__ mean, const float* __restrict__ var,
        float* __restrict__ out_flat,             // [256][HW] f32
        unsigned short* __restrict__ out_padh) {  // optional bf16 planes
    __shared__ __align__(16) unsigned short Bs[32][40];
    __shared__ float scs[256], bis[256];
    int b = blockIdx.x;
    int xcd = b & 7, slot = b >> 3;
    int nt = (xcd << 6) + slot;
    int hrow = nt >> 2, pc0 = (nt & 3) << 5;
    int tid = threadIdx.x;
    int wv = tid >> 6, lane = tid & 63;
    int lr = lane & 15, lg = lane >> 4;
    int pxl = tid & 31, cg = tid >> 5;
    {
        float sc = gam[tid] * rsqrtf(var[tid] + 1e-5f);
        scs[tid] = sc;
        bis[tid] = bet[tid] - mean[tid] * sc;
    }
    f32x4 acc[4][2];
#pragma unroll
    for (int i = 0; i < 4; ++i)
#pragma unroll
        for (int j = 0; j < 2; ++j) acc[i][j] = (f32x4){0.f, 0.f, 0.f, 0.f};

    for (int kt = 0; kt < 9; ++kt) {
        int dy = kt / 3 - 1, dx = kt % 3 - 1;
        const unsigned short* src = inh + (size_t)(hrow + dy + 1) * SH + (pc0 + pxl + dx + 1);
        const unsigned short* wk  = wTh + (size_t)kt * 65536;
        for (int ks = 0; ks < 256; ks += 32) {
            __syncthreads();
            unsigned short pk[4];
#pragma unroll
            for (int e = 0; e < 4; ++e) {
                int c = ks + (cg << 2) + e;
                pk[e] = src[(size_t)c * PSH];
            }
            *(short4*)&Bs[pxl][cg << 2] = *(short4*)pk;
            __syncthreads();
            bf16x8 af[4], bfr[2];
#pragma unroll
            for (int mi = 0; mi < 4; ++mi) {
                int o = (wv << 6) + (mi << 4) + lr;
                af[mi] = *(const bf16x8*)(wk + (size_t)o * 256 + ks + (lg << 3));
            }
#pragma unroll
            for (int ni = 0; ni < 2; ++ni) {
                int n = (ni << 4) + lr;
                bfr[ni] = *(const bf16x8*)(&Bs[n][lg << 3]);
            }
#pragma unroll
            for (int mi = 0; mi < 4; ++mi)
#pragma unroll
                for (int ni = 0; ni < 2; ++ni)
                    acc[mi][ni] = __builtin_amdgcn_mfma_f32_16x16x32_bf16(
                        af[mi], bfr[ni], acc[mi][ni], 0, 0, 0);
        }
    }
    size_t rowb = (size_t)(hrow + 1) * SH;
#pragma unroll
    for (int mi = 0; mi < 4; ++mi)
#pragma unroll
        for (int ni = 0; ni < 2; ++ni)
#pragma unroll
            for (int r = 0; r < 4; ++r) {
                int o   = (wv << 6) + (mi << 4) + (lg << 2) + r;
                int pxx = pc0 + (ni << 4) + lr;
                float rv = fmaxf(acc[mi][ni][r] * scs[o] + bis[o], 0.0f);
                out_flat[(size_t)o * HW + (hrow << 7) + pxx] = rv;
                if (out_padh)
                    out_padh[(size_t)o * PSH + rowb + pxx + 1] = f2bf(rv);
            }
}

extern "C" void kernel_launch(void* const* d_in, const int* in_sizes, int n_in,
                              void* d_out, int out_size, void* d_ws, size_t ws_size,
                              hipStream_t stream) {
    const float* x     = (const float*)d_in[0];
    const float* llf   = (const float*)d_in[1];
    const float* fm_w  = (const float*)d_in[2];
    const float* fs_w  = (const float*)d_in[3];
    const float* p_w   = (const float*)d_in[4];
    const float* p_b   = (const float*)d_in[5];
    const float* dc_w  = (const float*)d_in[6];
    const float* lc1_w = (const float*)d_in[7];
    const float* bn1g  = (const float*)d_in[8];
    const float* bn1b  = (const float*)d_in[9];
    const float* bn1m  = (const float*)d_in[10];
    const float* bn1v  = (const float*)d_in[11];
    const float* lc2_w = (const float*)d_in[12];
    const float* bn2g  = (const float*)d_in[13];
    const float* bn2b  = (const float*)d_in[14];
    const float* bn2m  = (const float*)d_in[15];
    const float* bn2v  = (const float*)d_in[16];
    float* out1 = (float*)d_out;
    float* out2 = out1 + (size_t)256 * HW;

    // d_out is now WRITE-ONLY (pure outputs). All scratch lives in ws.
    // Gate 79,839,232 B was verified available in rounds 2-3.
    if (ws_size < 79839232u) return;
    char* ws = (char*)d_ws;
    // ccT [0, 17,305,600): bf16 [130*130][512]; written by cvtT (ch0-255, all px),
    //   cfmfma (ch256+ interior), ringT (ch256+ ring); read by off_part/fam4.
    unsigned short* ccT   = (unsigned short*)ws;
    // V region [17,305,600, 34,877,440):
    //   ccpad f32 (17,305,600) [upsample -> cvtT], then
    //   vbuf  f32 (16,777,216) [vmfma -> u_matmul], then
    //   famh @+0 (8,785,920) and up1h @+8,785,920 (8,785,920)
    float*          ccpad = (float*)(ws + 17305600);
    float*          vbuf  = (float*)(ws + 17305600);
    unsigned short* famh  = (unsigned short*)(ws + 17305600);
    unsigned short* up1h  = (unsigned short*)(ws + 26091520);
    // llfT [34,877,440, 43,266,048)
    unsigned short* llfT  = (unsigned short*)(ws + 34877440);
    // uT   [43,266,048, 51,654,656)
    unsigned short* uT    = (unsigned short*)(ws + 43266048);
    unsigned short* fmwh  = (unsigned short*)(ws + 51654656);   // 131,072
    unsigned short* fswh  = (unsigned short*)(ws + 51785728);   // 131,072
    // U region [51,916,800, 68,694,016):
    //   ubuf f32 (16,777,216) [u_matmul -> cvtT_flat], then
    //   pbuf (8,388,608), IDX (2,359,296), WT (2,359,296)
    float*          ubuf  = (float*)(ws + 51916800);
    float*          pbuf  = (float*)(ws + 51916800);
    int4*           IDX   = (int4*)  (ws + 60305408);
    float4*         WT    = (float4*)(ws + 62664704);
    // weights (never aliased)
    unsigned short* dcwTh  = (unsigned short*)(ws + 68694016);  // 2,359,296
    unsigned short* lcw1Th = (unsigned short*)(ws + 71053312);  // 1,179,648
    unsigned short* lcw2Th = (unsigned short*)(ws + 72232960);  // 1,179,648
    unsigned short* pwTh   = (unsigned short*)(ws + 73412608);  //   294,912 (ends 73,707,520)

    upsample_k<<<dim3(67, 256), 256, 0, stream>>>(x, ccpad);
    cvtT_k<<<dim3(16900), 256, 0, stream>>>(ccpad, ccT);          // x -> ccT[:, :256]; ccpad dead
    cvtT_flat_k<<<dim3(16384), 256, 0, stream>>>(llf, llfT, HW);
    w2bf_k<<<dim3(256), 256, 0, stream>>>(fm_w, fs_w, fmwh, fswh);
    vmfma_k<<<dim3(512), 256, 0, stream>>>(llfT, fmwh, vbuf);     // llfT dead after
    u_matmul_k<<<dim3(2, 256), 256, 0, stream>>>(llf, vbuf, ubuf);  // vbuf dead after
    cvtT_flat_k<<<dim3(16384), 256, 0, stream>>>(ubuf, uT, HW);   // ubuf dead after
    tr_ocK_k<<<dim3(4608), 256, 0, stream>>>(dc_w, dcwTh, 512);
    tr_ocK_k<<<dim3(2304), 256, 0, stream>>>(lc1_w, lcw1Th, 256);
    tr_ocK_k<<<dim3(2304), 256, 0, stream>>>(lc2_w, lcw2Th, 256);
    tr_pw_k<<<dim3(576), 256, 0, stream>>>(p_w, pwTh);
    cfmfma_k<<<dim3(512), 256, 0, stream>>>(uT, fswh, ccT);       // Cf -> ccT[:, 256:]; uT dead
    ringT_k<<<dim3(520), 256, 0, stream>>>(ccT);                  // Cf ring = 0
    off_part_k<<<dim3(512), 256, 0, stream>>>(ccT, pwTh, pbuf);
    make_idx_k<<<dim3(576), 256, 0, stream>>>(pbuf, p_b, IDX, WT);  // pbuf dead after
    zero_ring_h_k<<<dim3(521), 256, 0, stream>>>(famh, 256);
    zero_ring_h_k<<<dim3(521), 256, 0, stream>>>(up1h, 256);
    fam4_k<<<dim3(512), 256, 0, stream>>>(ccT, dcwTh, IDX, WT, famh);  // ccT dead after
    conv2_k<<<dim3(512), 256, 0, stream>>>(famh, lcw1Th, bn1g, bn1b, bn1m, bn1v,
                                           out1, up1h);           // famh dead after
    conv2_k<<<dim3(512), 256, 0, stream>>>(up1h, lcw2Th, bn2g, bn2b, bn2m, bn2v,
                                           out2, nullptr);
}

// Round 9
// 621.095 us; speedup vs baseline: 1.7275x; 1.0670x over previous
//
#include <hip/hip_runtime.h>
#include <math.h>

#define HW   16384           // 128*128
#define PS   16900           // 130*130 f32 padded plane
#define PSH  17160           // 130*132 bf16 padded plane (stride 132)
#define SH   132

typedef __attribute__((ext_vector_type(8))) short bf16x8;
typedef __attribute__((ext_vector_type(4))) float f32x4;

__device__ inline unsigned short f2bf(float x) {
    unsigned int u = __float_as_uint(x);
    unsigned int r = (u + 0x7fffu + ((u >> 16) & 1u)) >> 16;
    return (unsigned short)r;
}
__device__ inline float bf2f(unsigned short h) {
    return __uint_as_float(((unsigned int)h) << 16);
}

// ---- zero the pad ring of nch bf16 padded planes (stride 132) --------------
__global__ __launch_bounds__(256) void zero_ring_h_k(unsigned short* __restrict__ base, int nch) {
    int t = blockIdx.x * 256 + threadIdx.x;
    if (t >= nch * 520) return;
    int ch = t / 520, rp = t - ch * 520;
    int row, col;
    if (rp < 132)      { row = 0;   col = rp; }
    else if (rp < 264) { row = 129; col = rp - 132; }
    else {
        int rem = rp - 264;
        if (rem >= 256) return;            // rows 1..128 only (no OOB spill)
        row = 1 + (rem >> 1); col = (rem & 1) ? 129 : 0;
    }
    base[(size_t)ch * PSH + row * SH + col] = 0;
}

// ---- zero ccT ring pixels for channels 256..511 (Cf) -----------------------
__global__ __launch_bounds__(256) void ringT_k(unsigned short* __restrict__ ccT) {
    int t = blockIdx.x * 256 + threadIdx.x;
    if (t >= 520 * 256) return;
    int ci = t & 255, rp = t >> 8;
    int row, col;
    if (rp < 130)      { row = 0;   col = rp; }
    else if (rp < 260) { row = 129; col = rp - 130; }
    else {
        int rem = rp - 260;
        if (rem >= 256) return;            // rows 1..128 only (no OOB spill)
        row = 1 + (rem >> 1); col = (rem & 1) ? 129 : 0;
    }
    ccT[(size_t)(row * 130 + col) * 512 + 256 + ci] = 0;
}

// ---- bilinear upsample (align_corners) 32x32 -> 128x128, into 256 f32 planes
__global__ __launch_bounds__(256) void upsample_k(const float* __restrict__ x,
                                                  float* __restrict__ ccpad) {
    int c = blockIdx.y;
    int idx = blockIdx.x * 256 + threadIdx.x;
    if (idx >= PS) return;
    int r = idx / 130, s = idx - r * 130;
    float val = 0.0f;
    if (r >= 1 && r <= 128 && s >= 1 && s <= 128) {
        int i = r - 1, j = s - 1;
        float yf = (float)i * (31.0f / 127.0f);
        float xf = (float)j * (31.0f / 127.0f);
        int y0 = min((int)yf, 31); int y1 = min(y0 + 1, 31);
        int x0 = min((int)xf, 31); int x1 = min(x0 + 1, 31);
        float wy = yf - (float)y0, wx = xf - (float)x0;
        const float* xc = x + (size_t)c * 1024;
        float a = xc[y0 * 32 + x0] * (1.0f - wx) + xc[y0 * 32 + x1] * wx;
        float b = xc[y1 * 32 + x0] * (1.0f - wx) + xc[y1 * 32 + x1] * wx;
        val = a * (1.0f - wy) + b * wy;
    }
    ccpad[(size_t)c * PS + idx] = val;
}

// ---- flat transpose+cvt: src f32 [256][npx] -> dst bf16 [npx][256] ---------
__global__ __launch_bounds__(256) void cvtT_flat_k(const float* __restrict__ src,
                                                   unsigned short* __restrict__ dst,
                                                   int npx) {
    int t = blockIdx.x * 256 + threadIdx.x;    // (pix, c), c fastest
    int c = t & 255, pix = t >> 8;
    dst[t] = f2bf(src[(size_t)c * npx + pix]);
}

// ---- ccpad f32 planes (256 ch, stride 130) -> ccT[pix][512] ch 0..255 ------
__global__ __launch_bounds__(256) void cvtT_k(const float* __restrict__ src,
                                              unsigned short* __restrict__ dst) {
    int t = blockIdx.x * 256 + threadIdx.x;    // 130*130*256 exactly
    int c = t & 255, pix = t >> 8;
    dst[(size_t)pix * 512 + c] = f2bf(src[(size_t)c * PS + pix]);
}

// ---- fm_w / fs_w (256x256 f32) -> bf16 -------------------------------------
__global__ __launch_bounds__(256) void w2bf_k(const float* __restrict__ a,
                                              const float* __restrict__ b,
                                              unsigned short* __restrict__ da,
                                              unsigned short* __restrict__ db) {
    int t = blockIdx.x * 256 + threadIdx.x;
    if (t >= 65536) return;
    da[t] = f2bf(a[t]);
    db[t] = f2bf(b[t]);
}

// ---- u[c,h,w] = sum_k L[c,h,k]*v[c,k,w] + L[c,h,w] (f32) -------------------
__global__ __launch_bounds__(256) void u_matmul_k(const float* __restrict__ llf,
                                                  const float* __restrict__ v,
                                                  float* __restrict__ u) {
    int c = blockIdx.y;
    const float* L = llf + (size_t)c * HW;
    const float* V = v   + (size_t)c * HW;
    float*       U = u   + (size_t)c * HW;
    int tid = threadIdx.x;
    int ty = tid >> 4, tx = tid & 15;
    int r0 = (blockIdx.x << 6) + (ty << 2);
    int w0 = tx << 3;
    float acc[4][8] = {};
    for (int k = 0; k < 128; ++k) {
        float a[4];
#pragma unroll
        for (int i = 0; i < 4; ++i) a[i] = L[(r0 + i) * 128 + k];
        float4 b0 = *(const float4*)(V + k * 128 + w0);
        float4 b1 = *(const float4*)(V + k * 128 + w0 + 4);
        float bv[8] = {b0.x, b0.y, b0.z, b0.w, b1.x, b1.y, b1.z, b1.w};
#pragma unroll
        for (int i = 0; i < 4; ++i)
#pragma unroll
            for (int j = 0; j < 8; ++j) acc[i][j] += a[i] * bv[j];
    }
#pragma unroll
    for (int i = 0; i < 4; ++i) {
#pragma unroll
        for (int j = 0; j < 8; ++j) acc[i][j] += L[(r0 + i) * 128 + w0 + j];
        *(float4*)(U + (r0 + i) * 128 + w0)     = make_float4(acc[i][0], acc[i][1], acc[i][2], acc[i][3]);
        *(float4*)(U + (r0 + i) * 128 + w0 + 4) = make_float4(acc[i][4], acc[i][5], acc[i][6], acc[i][7]);
    }
}

// ---- weights (O,C,3,3) f32 -> [k][o][c] bf16 (O=256) -----------------------
__global__ __launch_bounds__(256) void tr_ocK_k(const float* __restrict__ w,
                                                unsigned short* __restrict__ dst, int C) {
    int t = blockIdx.x * 256 + threadIdx.x;
    if (t >= 9 * 256 * C) return;
    int c = t % C; int rest = t / C; int o = rest & 255; int k = rest >> 8;
    dst[t] = f2bf(w[(size_t)o * C * 9 + c * 9 + k]);
}

// ---- p_w (18,512,3,3) f32 -> [k][32][512] bf16, zero-padded to 32 o --------
__global__ __launch_bounds__(256) void tr_pw_k(const float* __restrict__ w,
                                               unsigned short* __restrict__ dst) {
    int t = blockIdx.x * 256 + threadIdx.x;
    if (t >= 9 * 32 * 512) return;
    int c = t & 511; int rest = t >> 9; int o = rest & 31; int k = rest >> 5;
    dst[t] = (o < 18) ? f2bf(w[(size_t)o * 4608 + c * 9 + k]) : (unsigned short)0;
}

// ============ 1x1 GEMM (K=256) 256o x 32px MFMA + sigmoid -> f32 planes =====
__global__ __launch_bounds__(256, 2) void vmfma_k(
        const unsigned short* __restrict__ inT,   // [HW][256] bf16
        const unsigned short* __restrict__ wh,    // [256][256] bf16
        float* __restrict__ vout) {               // [256][HW] f32
    __shared__ __align__(16) unsigned short Bs[32][72];
    int b = blockIdx.x;
    int xcd = b & 7, sl = b >> 3;
    int nt = (xcd << 6) + sl;
    int hrow = nt >> 2, pc0 = (nt & 3) << 5;
    int tid = threadIdx.x;
    int wv = tid >> 6, lane = tid & 63;
    int lr = lane & 15, lg = lane >> 4;
    int pxl = tid & 31, grp = tid >> 5;
    int p = (hrow << 7) + pc0 + pxl;
    f32x4 acc[4][2];
#pragma unroll
    for (int i = 0; i < 4; ++i)
#pragma unroll
        for (int j = 0; j < 2; ++j) acc[i][j] = (f32x4){0.f, 0.f, 0.f, 0.f};
    for (int ks = 0; ks < 256; ks += 64) {
        __syncthreads();
        *(bf16x8*)&Bs[pxl][grp << 3] =
            *(const bf16x8*)(inT + (size_t)p * 256 + ks + (grp << 3));
        __syncthreads();
#pragma unroll
        for (int s = 0; s < 2; ++s) {
            int ko = ks + (s << 5) + (lg << 3);
            bf16x8 af[4], bfr[2];
#pragma unroll
            for (int mi = 0; mi < 4; ++mi)
                af[mi] = *(const bf16x8*)(wh + (size_t)((wv << 6) + (mi << 4) + lr) * 256 + ko);
#pragma unroll
            for (int ni = 0; ni < 2; ++ni)
                bfr[ni] = *(const bf16x8*)(&Bs[(ni << 4) + lr][(s << 5) + (lg << 3)]);
#pragma unroll
            for (int mi = 0; mi < 4; ++mi)
#pragma unroll
                for (int ni = 0; ni < 2; ++ni)
                    acc[mi][ni] = __builtin_amdgcn_mfma_f32_16x16x32_bf16(
                        af[mi], bfr[ni], acc[mi][ni], 0, 0, 0);
        }
    }
#pragma unroll
    for (int mi = 0; mi < 4; ++mi)
#pragma unroll
        for (int ni = 0; ni < 2; ++ni)
#pragma unroll
            for (int r = 0; r < 4; ++r) {
                int o   = (wv << 6) + (mi << 4) + (lg << 2) + r;
                int pxx = pc0 + (ni << 4) + lr;
                vout[(size_t)o * HW + (hrow << 7) + pxx] =
                    1.0f / (1.0f + expf(-acc[mi][ni][r]));
            }
}

// ============ 1x1 GEMM (K=256) Cf -> ccT channels 256..511 ==================
__global__ __launch_bounds__(256, 2) void cfmfma_k(
        const unsigned short* __restrict__ inT,   // uT [HW][256] bf16
        const unsigned short* __restrict__ wh,    // fs_w [256][256] bf16
        unsigned short* __restrict__ ccT) {       // [130*130][512] bf16
    __shared__ __align__(16) unsigned short Bs[32][72];
    int b = blockIdx.x;
    int xcd = b & 7, sl = b >> 3;
    int nt = (xcd << 6) + sl;
    int hrow = nt >> 2, pc0 = (nt & 3) << 5;
    int tid = threadIdx.x;
    int wv = tid >> 6, lane = tid & 63;
    int lr = lane & 15, lg = lane >> 4;
    int pxl = tid & 31, grp = tid >> 5;
    int p = (hrow << 7) + pc0 + pxl;
    f32x4 acc[4][2];
#pragma unroll
    for (int i = 0; i < 4; ++i)
#pragma unroll
        for (int j = 0; j < 2; ++j) acc[i][j] = (f32x4){0.f, 0.f, 0.f, 0.f};
    for (int ks = 0; ks < 256; ks += 64) {
        __syncthreads();
        *(bf16x8*)&Bs[pxl][grp << 3] =
            *(const bf16x8*)(inT + (size_t)p * 256 + ks + (grp << 3));
        __syncthreads();
#pragma unroll
        for (int s = 0; s < 2; ++s) {
            int ko = ks + (s << 5) + (lg << 3);
            bf16x8 af[4], bfr[2];
#pragma unroll
            for (int mi = 0; mi < 4; ++mi)
                af[mi] = *(const bf16x8*)(wh + (size_t)((wv << 6) + (mi << 4) + lr) * 256 + ko);
#pragma unroll
            for (int ni = 0; ni < 2; ++ni)
                bfr[ni] = *(const bf16x8*)(&Bs[(ni << 4) + lr][(s << 5) + (lg << 3)]);
#pragma unroll
            for (int mi = 0; mi < 4; ++mi)
#pragma unroll
                for (int ni = 0; ni < 2; ++ni)
                    acc[mi][ni] = __builtin_amdgcn_mfma_f32_16x16x32_bf16(
                        af[mi], bfr[ni], acc[mi][ni], 0, 0, 0);
        }
    }
#pragma unroll
    for (int mi = 0; mi < 4; ++mi)
#pragma unroll
        for (int ni = 0; ni < 2; ++ni) {
            int pxx = pc0 + (ni << 4) + lr;
            int pix = (hrow + 1) * 130 + pxx + 1;
            unsigned short pk[4];
#pragma unroll
            for (int r = 0; r < 4; ++r) pk[r] = f2bf(acc[mi][ni][r]);
            *(ushort4*)(ccT + (size_t)pix * 512 + 256 + (wv << 6) + (mi << 4) + (lg << 2))
                = *(ushort4*)pk;
        }
}

// ============ offset conv 512->18: channel-split partials, ccT staging ======
__global__ __launch_bounds__(256, 2) void off_part_k(
        const unsigned short* __restrict__ ccT,   // [130*130][512] bf16
        const unsigned short* __restrict__ pwTh,  // [9][32][512] bf16
        float* __restrict__ pbuf) {               // [4][32][HW] f32
    __shared__ __align__(16) unsigned short Bs[128][40];
    int b = blockIdx.x;
    int xcd = b & 7, slot = b >> 3;               // 64 slots
    int hrow = (xcd << 4) + (slot >> 2);
    int cg = slot & 3, c0 = cg << 7;
    int tid = threadIdx.x;
    int wv = tid >> 6, lane = tid & 63;
    int wr = wv >> 1, wc = wv & 1;                // o-half(16) x px-half(64)
    int lr = lane & 15, lg = lane >> 4;
    int px = tid & 127, sg = tid >> 7;            // sg in 0..1
    f32x4 acc[4];
#pragma unroll
    for (int j = 0; j < 4; ++j) acc[j] = (f32x4){0.f, 0.f, 0.f, 0.f};

    for (int kt = 0; kt < 9; ++kt) {
        int dy = kt / 3 - 1, dx = kt % 3 - 1;
        int pixb = (hrow + dy + 1) * 130 + dx + 1;
        for (int ksl = 0; ksl < 128; ksl += 32) {
            __syncthreads();
#pragma unroll
            for (int q = 0; q < 2; ++q) {
                int cofs = (q << 4) + (sg << 3);
                *(bf16x8*)&Bs[px][cofs] =
                    *(const bf16x8*)(ccT + (size_t)(pixb + px) * 512 + c0 + ksl + cofs);
            }
            __syncthreads();
            bf16x8 af, bfr[4];
            af = *(const bf16x8*)(pwTh + (size_t)kt * 16384
                                  + (size_t)((wr << 4) + lr) * 512 + c0 + ksl + (lg << 3));
#pragma unroll
            for (int ni = 0; ni < 4; ++ni) {
                int n = (wc << 6) + (ni << 4) + lr;
                bfr[ni] = *(const bf16x8*)(&Bs[n][lg << 3]);
            }
#pragma unroll
            for (int ni = 0; ni < 4; ++ni)
                acc[ni] = __builtin_amdgcn_mfma_f32_16x16x32_bf16(af, bfr[ni], acc[ni], 0, 0, 0);
        }
    }
#pragma unroll
    for (int ni = 0; ni < 4; ++ni)
#pragma unroll
        for (int r = 0; r < 4; ++r) {
            int o = (wr << 4) + (lg << 2) + r;
            int p = (hrow << 7) + (wc << 6) + (ni << 4) + lr;
            pbuf[(size_t)((cg << 5) + o) * HW + p] = acc[ni][r];
        }
}

// ---- per-(pixel,k): sum 4 partials; IDX = pixel-index*512 into ccT ---------
__global__ __launch_bounds__(256) void make_idx_k(const float* __restrict__ pbuf,
                                                  const float* __restrict__ pb,
                                                  int4* __restrict__ IDX,
                                                  float4* __restrict__ WT) {
    int t = blockIdx.x * 256 + threadIdx.x;
    if (t >= 9 * HW) return;
    int k = t >> 14, p = t & 16383;
    int h = p >> 7, w = p & 127;
    float ox = 0.f, oy = 0.f;
#pragma unroll
    for (int cg = 0; cg < 4; ++cg) {
        ox += pbuf[(size_t)((cg << 5) + k) * HW + p];
        oy += pbuf[(size_t)((cg << 5) + 9 + k) * HW + p];
    }
    float px = ox + pb[k]     + (float)(k / 3 - 1) + (float)(h + 1);
    float py = oy + pb[9 + k] + (float)(k % 3 - 1) + (float)(w + 1);
    float fx = floorf(px), fy = floorf(py);
    float x0 = fminf(fmaxf(fx,        0.f), 129.f);
    float x1 = fminf(fmaxf(fx + 1.0f, 0.f), 129.f);
    float y0 = fminf(fmaxf(fy,        0.f), 129.f);
    float y1 = fminf(fmaxf(fy + 1.0f, 0.f), 129.f);
    float pxc = fminf(fmaxf(px, 0.f), 129.f);
    float pyc = fminf(fmaxf(py, 0.f), 129.f);
    float gx0 = 1.0f + x0 - pxc, gx1 = 1.0f - x1 + pxc;
    float gy0 = 1.0f + y0 - pyc, gy1 = 1.0f - y1 + pyc;
    int ix0 = (int)x0, ix1 = (int)x1, iy0 = (int)y0, iy1 = (int)y1;
    IDX[t] = make_int4((ix0 * 130 + iy0) << 9, (ix1 * 130 + iy1) << 9,
                       (ix0 * 130 + iy1) << 9, (ix1 * 130 + iy0) << 9);
    WT[t]  = make_float4(gx0 * gy0, gx1 * gy1, gx0 * gy1, gx1 * gy0);
}

// ============ deformable contraction v5: 256o x 64px, A via LDS =============
// 512 threads (8 waves), grid 256 (1 block/CU). VMEM instrs/output -33% vs
// fam4: A-tile (256o x 64ch, 32KB) staged coalesced into LDS once per chunk
// and read as frags via ds_read_b128; gather amortized over 2x the px.
__global__ __launch_bounds__(512, 2) void fam5_k(
        const unsigned short* __restrict__ ccT,    // [130*130][512] bf16
        const unsigned short* __restrict__ dcwTh,  // [9][256][512] bf16
        const int4* __restrict__ IDX, const float4* __restrict__ WT,
        unsigned short* __restrict__ famh) {       // 256 bf16 planes PSH
    __shared__ __align__(16) unsigned short As[256][72];   // 36,864 B (o-major)
    __shared__ __align__(16) unsigned short Bs[64][72];    //  9,216 B (px-major)
    int b = blockIdx.x;                 // 256 blocks
    int xcd = b & 7, sl = b >> 3;       // 32 slots per XCD
    int nt = (xcd << 5) + sl;           // XCD owns 16 contiguous hrows
    int hrow = nt >> 1, pc0 = (nt & 1) << 6;
    int tid = threadIdx.x;
    int wv = tid >> 6, lane = tid & 63;
    int wo = wv >> 1, wp = wv & 1;      // o-quarter (64) x px-half (32)
    int lr = lane & 15, lg = lane >> 4;
    int pxl = tid & 63, grp = tid >> 6; // gather: 64 px x 8 ch-groups of 8
    int cofs = tid & 7, orow = tid >> 3;// A-stage: 64 o-rows x 8 x 16B
    int p = (hrow << 7) + pc0 + pxl;
    f32x4 acc[4][2];
#pragma unroll
    for (int i = 0; i < 4; ++i)
#pragma unroll
        for (int j = 0; j < 2; ++j) acc[i][j] = (f32x4){0.f, 0.f, 0.f, 0.f};

    for (int kt = 0; kt < 9; ++kt) {
        int4   id = IDX[(kt << 14) + p];
        float4 wt = WT [(kt << 14) + p];
        const unsigned short* dwk = dcwTh + (size_t)kt * 131072;
        for (int ks = 0; ks < 512; ks += 64) {
            __syncthreads();
            // stage A tile (256o x 64ch) coalesced global -> LDS
#pragma unroll
            for (int j = 0; j < 4; ++j) {
                int o = orow + (j << 6);
                *(bf16x8*)&As[o][cofs << 3] =
                    *(const bf16x8*)(dwk + (size_t)o * 512 + ks + (cofs << 3));
            }
            // stage B: bilinear gather (16B/corner), weight in f32, pack bf16
            {
                int cb = ks + (grp << 3);
                bf16x8 v0 = *(const bf16x8*)(ccT + id.x + cb);
                bf16x8 v1 = *(const bf16x8*)(ccT + id.y + cb);
                bf16x8 v2 = *(const bf16x8*)(ccT + id.z + cb);
                bf16x8 v3 = *(const bf16x8*)(ccT + id.w + cb);
                unsigned short pk[8];
#pragma unroll
                for (int e = 0; e < 8; ++e) {
                    float val = wt.x * bf2f((unsigned short)v0[e])
                              + wt.y * bf2f((unsigned short)v1[e])
                              + wt.z * bf2f((unsigned short)v2[e])
                              + wt.w * bf2f((unsigned short)v3[e]);
                    pk[e] = f2bf(val);
                }
                *(bf16x8*)&Bs[pxl][grp << 3] = *(bf16x8*)pk;
            }
            __syncthreads();
#pragma unroll
            for (int s = 0; s < 2; ++s) {
                int ko = (s << 5) + (lg << 3);
                bf16x8 af[4], bfr[2];
#pragma unroll
                for (int mi = 0; mi < 4; ++mi)
                    af[mi] = *(const bf16x8*)(&As[(wo << 6) + (mi << 4) + lr][ko]);
#pragma unroll
                for (int ni = 0; ni < 2; ++ni)
                    bfr[ni] = *(const bf16x8*)(&Bs[(wp << 5) + (ni << 4) + lr][ko]);
#pragma unroll
                for (int mi = 0; mi < 4; ++mi)
#pragma unroll
                    for (int ni = 0; ni < 2; ++ni)
                        acc[mi][ni] = __builtin_amdgcn_mfma_f32_16x16x32_bf16(
                            af[mi], bfr[ni], acc[mi][ni], 0, 0, 0);
            }
        }
    }
    size_t rowb = (size_t)(hrow + 1) * SH;
#pragma unroll
    for (int mi = 0; mi < 4; ++mi)
#pragma unroll
        for (int ni = 0; ni < 2; ++ni)
#pragma unroll
            for (int r = 0; r < 4; ++r) {
                int o   = (wo << 6) + (mi << 4) + (lg << 2) + r;
                int pxx = pc0 + (wp << 5) + (ni << 4) + lr;
                float cf = bf2f(ccT[(size_t)((hrow + 1) * 130 + pxx + 1) * 512 + 256 + o]);
                famh[(size_t)o * PSH + rowb + pxx + 1] = f2bf(acc[mi][ni][r] + cf);
            }
}

// ============ 3x3 conv 256->256: full-M 256o x 32px tiles + BN + ReLU =======
__global__ __launch_bounds__(256, 2) void conv2_k(
        const unsigned short* __restrict__ inh,   // 256 bf16 planes PSH, ring=0
        const unsigned short* __restrict__ wTh,   // [9][256][256] bf16
        const float* __restrict__ gam, const float* __restrict__ bet,
        const float* __restrict__ mean, const float* __restrict__ var,
        float* __restrict__ out_flat,             // [256][HW] f32
        unsigned short* __restrict__ out_padh) {  // optional bf16 planes
    __shared__ __align__(16) unsigned short Bs[32][40];
    __shared__ float scs[256], bis[256];
    int b = blockIdx.x;
    int xcd = b & 7, slot = b >> 3;
    int nt = (xcd << 6) + slot;
    int hrow = nt >> 2, pc0 = (nt & 3) << 5;
    int tid = threadIdx.x;
    int wv = tid >> 6, lane = tid & 63;
    int lr = lane & 15, lg = lane >> 4;
    int pxl = tid & 31, cg = tid >> 5;
    {
        float sc = gam[tid] * rsqrtf(var[tid] + 1e-5f);
        scs[tid] = sc;
        bis[tid] = bet[tid] - mean[tid] * sc;
    }
    f32x4 acc[4][2];
#pragma unroll
    for (int i = 0; i < 4; ++i)
#pragma unroll
        for (int j = 0; j < 2; ++j) acc[i][j] = (f32x4){0.f, 0.f, 0.f, 0.f};

    for (int kt = 0; kt < 9; ++kt) {
        int dy = kt / 3 - 1, dx = kt % 3 - 1;
        const unsigned short* src = inh + (size_t)(hrow + dy + 1) * SH + (pc0 + pxl + dx + 1);
        const unsigned short* wk  = wTh + (size_t)kt * 65536;
        for (int ks = 0; ks < 256; ks += 32) {
            __syncthreads();
            unsigned short pk[4];
#pragma unroll
            for (int e = 0; e < 4; ++e) {
                int c = ks + (cg << 2) + e;
                pk[e] = src[(size_t)c * PSH];
            }
            *(short4*)&Bs[pxl][cg << 2] = *(short4*)pk;
            __syncthreads();
            bf16x8 af[4], bfr[2];
#pragma unroll
            for (int mi = 0; mi < 4; ++mi) {
                int o = (wv << 6) + (mi << 4) + lr;
                af[mi] = *(const bf16x8*)(wk + (size_t)o * 256 + ks + (lg << 3));
            }
#pragma unroll
            for (int ni = 0; ni < 2; ++ni) {
                int n = (ni << 4) + lr;
                bfr[ni] = *(const bf16x8*)(&Bs[n][lg << 3]);
            }
#pragma unroll
            for (int mi = 0; mi < 4; ++mi)
#pragma unroll
                for (int ni = 0; ni < 2; ++ni)
                    acc[mi][ni] = __builtin_amdgcn_mfma_f32_16x16x32_bf16(
                        af[mi], bfr[ni], acc[mi][ni], 0, 0, 0);
        }
    }
    size_t rowb = (size_t)(hrow + 1) * SH;
#pragma unroll
    for (int mi = 0; mi < 4; ++mi)
#pragma unroll
        for (int ni = 0; ni < 2; ++ni)
#pragma unroll
            for (int r = 0; r < 4; ++r) {
                int o   = (wv << 6) + (mi << 4) + (lg << 2) + r;
                int pxx = pc0 + (ni << 4) + lr;
                float rv = fmaxf(acc[mi][ni][r] * scs[o] + bis[o], 0.0f);
                out_flat[(size_t)o * HW + (hrow << 7) + pxx] = rv;
                if (out_padh)
                    out_padh[(size_t)o * PSH + rowb + pxx + 1] = f2bf(rv);
            }
}

extern "C" void kernel_launch(void* const* d_in, const int* in_sizes, int n_in,
                              void* d_out, int out_size, void* d_ws, size_t ws_size,
                              hipStream_t stream) {
    const float* x     = (const float*)d_in[0];
    const float* llf   = (const float*)d_in[1];
    const float* fm_w  = (const float*)d_in[2];
    const float* fs_w  = (const float*)d_in[3];
    const float* p_w   = (const float*)d_in[4];
    const float* p_b   = (const float*)d_in[5];
    const float* dc_w  = (const float*)d_in[6];
    const float* lc1_w = (const float*)d_in[7];
    const float* bn1g  = (const float*)d_in[8];
    const float* bn1b  = (const float*)d_in[9];
    const float* bn1m  = (const float*)d_in[10];
    const float* bn1v  = (const float*)d_in[11];
    const float* lc2_w = (const float*)d_in[12];
    const float* bn2g  = (const float*)d_in[13];
    const float* bn2b  = (const float*)d_in[14];
    const float* bn2m  = (const float*)d_in[15];
    const float* bn2v  = (const float*)d_in[16];
    float* out1 = (float*)d_out;
    float* out2 = out1 + (size_t)256 * HW;

    // d_out is WRITE-ONLY (pure outputs). All scratch lives in ws.
    if (ws_size < 79839232u) return;
    char* ws = (char*)d_ws;
    unsigned short* ccT   = (unsigned short*)ws;                // [0, 17,305,600)
    float*          ccpad = (float*)(ws + 17305600);            // V region
    float*          vbuf  = (float*)(ws + 17305600);
    unsigned short* famh  = (unsigned short*)(ws + 17305600);
    unsigned short* up1h  = (unsigned short*)(ws + 26091520);
    unsigned short* llfT  = (unsigned short*)(ws + 34877440);
    unsigned short* uT    = (unsigned short*)(ws + 43266048);
    unsigned short* fmwh  = (unsigned short*)(ws + 51654656);   // 131,072
    unsigned short* fswh  = (unsigned short*)(ws + 51785728);   // 131,072
    float*          ubuf  = (float*)(ws + 51916800);            // U region
    float*          pbuf  = (float*)(ws + 51916800);
    int4*           IDX   = (int4*)  (ws + 60305408);
    float4*         WT    = (float4*)(ws + 62664704);
    unsigned short* dcwTh  = (unsigned short*)(ws + 68694016);  // 2,359,296
    unsigned short* lcw1Th = (unsigned short*)(ws + 71053312);  // 1,179,648
    unsigned short* lcw2Th = (unsigned short*)(ws + 72232960);  // 1,179,648
    unsigned short* pwTh   = (unsigned short*)(ws + 73412608);  //   294,912

    upsample_k<<<dim3(67, 256), 256, 0, stream>>>(x, ccpad);
    cvtT_k<<<dim3(16900), 256, 0, stream>>>(ccpad, ccT);          // ccpad dead after
    cvtT_flat_k<<<dim3(16384), 256, 0, stream>>>(llf, llfT, HW);
    w2bf_k<<<dim3(256), 256, 0, stream>>>(fm_w, fs_w, fmwh, fswh);
    vmfma_k<<<dim3(512), 256, 0, stream>>>(llfT, fmwh, vbuf);
    u_matmul_k<<<dim3(2, 256), 256, 0, stream>>>(llf, vbuf, ubuf);  // vbuf dead after
    cvtT_flat_k<<<dim3(16384), 256, 0, stream>>>(ubuf, uT, HW);   // ubuf dead after
    tr_ocK_k<<<dim3(4608), 256, 0, stream>>>(dc_w, dcwTh, 512);
    tr_ocK_k<<<dim3(2304), 256, 0, stream>>>(lc1_w, lcw1Th, 256);
    tr_ocK_k<<<dim3(2304), 256, 0, stream>>>(lc2_w, lcw2Th, 256);
    tr_pw_k<<<dim3(576), 256, 0, stream>>>(p_w, pwTh);
    cfmfma_k<<<dim3(512), 256, 0, stream>>>(uT, fswh, ccT);       // Cf -> ccT[:, 256:]
    ringT_k<<<dim3(520), 256, 0, stream>>>(ccT);                  // Cf ring = 0
    off_part_k<<<dim3(512), 256, 0, stream>>>(ccT, pwTh, pbuf);
    make_idx_k<<<dim3(576), 256, 0, stream>>>(pbuf, p_b, IDX, WT);
    zero_ring_h_k<<<dim3(521), 256, 0, stream>>>(famh, 256);
    zero_ring_h_k<<<dim3(521), 256, 0, stream>>>(up1h, 256);
    fam5_k<<<dim3(256), 512, 0, stream>>>(ccT, dcwTh, IDX, WT, famh);
    conv2_k<<<dim3(512), 256, 0, stream>>>(famh, lcw1Th, bn1g, bn1b, bn1m, bn1v,
                                           out1, up1h);
    conv2_k<<<dim3(512), 256, 0, stream>>>(up1h, lcw2Th, bn2g, bn2b, bn2m, bn2v,
                                           out2, nullptr);
}